// Round 1
// baseline (1958.328 us; speedup 1.0000x reference)
//
#include <hip/hip_runtime.h>
#include <hip/hip_bf16.h>
#include <math.h>

#define BQ 8
#define LQ 2048
#define DM 768
#define DI 1536
#define DS 128
#define NH 24
#define HD 64
#define CONVD 1792          // DI + 2*DS
#define NPROJ 3352          // 2*DI + 2*DS + NH
#define NPAD 3456           // NPROJ padded to 128
#define BL (BQ*LQ)          // 16384 tokens
#define CHUNK 32

using f32x4 = __attribute__((ext_vector_type(4))) float;
using frag8 = __attribute__((ext_vector_type(8))) short;
typedef __hip_bfloat16 bf16;

// ---- static scratch (module-load allocated; fully rewritten every launch) ----
__device__ __align__(16) bf16  g_u[(size_t)BL*DM];        // LN output, bf16
__device__ __align__(16) bf16  g_Win[(size_t)NPAD*DM];    // W_in cast+padded
__device__ __align__(16) float g_zx[(size_t)BL*NPAD];     // zxbcdt (fp32)
__device__ __align__(16) float g_xbc[(size_t)BL*CONVD];   // conv+silu out; cols 0..1535 later overlaid by gated y
__device__ __align__(16) float g_dA[BQ*NH*LQ];
__device__ __align__(16) float g_dt[BQ*NH*LQ];
__device__ __align__(16) bf16  g_yn[(size_t)BL*DI];       // RMSNorm out, bf16
__device__ __align__(16) bf16  g_Wout[(size_t)DM*DI];

__device__ __forceinline__ void gl_lds16(const void* g, void* l){
  __builtin_amdgcn_global_load_lds((const __attribute__((address_space(1))) unsigned int*)g,
                                   (__attribute__((address_space(3))) unsigned int*)l, 16, 0, 0);
}
__device__ __forceinline__ void gl_lds4(const void* g, void* l){
  __builtin_amdgcn_global_load_lds((const __attribute__((address_space(1))) unsigned int*)g,
                                   (__attribute__((address_space(3))) unsigned int*)l, 4, 0, 0);
}
__device__ __forceinline__ float silu_f(float v){ return v / (1.f + expf(-v)); }

// ---- weight casts ----
__global__ __launch_bounds__(256) void k_castWin(const float* __restrict__ W){
  int idx = blockIdx.x*256 + threadIdx.x;         // < NPAD*DM
  int row = idx / DM, col = idx % DM;
  float v = (row < NPROJ) ? W[(size_t)row*DM + col] : 0.f;
  g_Win[idx] = __float2bfloat16(v);
}
__global__ __launch_bounds__(256) void k_castWout(const float* __restrict__ W){
  int idx = blockIdx.x*256 + threadIdx.x;         // < DM*DI
  g_Wout[idx] = __float2bfloat16(W[idx]);
}

// ---- LayerNorm -> bf16 u ----
__global__ __launch_bounds__(256) void k_ln(const float* __restrict__ x,
                                            const float* __restrict__ lw,
                                            const float* __restrict__ lb){
  int r = blockIdx.x, tid = threadIdx.x;
  const float* xr = x + (size_t)r*DM;
  float v0 = xr[tid], v1 = xr[tid+256], v2 = xr[tid+512];
  float s = v0+v1+v2, q = v0*v0 + v1*v1 + v2*v2;
  __shared__ float red[8];
  #pragma unroll
  for (int o=32;o>0;o>>=1){ s += __shfl_down(s,o); q += __shfl_down(q,o); }
  if ((tid&63)==0){ red[tid>>6] = s; red[4+(tid>>6)] = q; }
  __syncthreads();
  float st = red[0]+red[1]+red[2]+red[3];
  float qt = red[4]+red[5]+red[6]+red[7];
  float mu = st * (1.f/DM);
  float var = qt * (1.f/DM) - mu*mu;
  float rs = rsqrtf(var + 1e-5f);
  bf16* ur = g_u + (size_t)r*DM;
  ur[tid]     = __float2bfloat16((v0-mu)*rs*lw[tid]     + lb[tid]);
  ur[tid+256] = __float2bfloat16((v1-mu)*rs*lw[tid+256] + lb[tid+256]);
  ur[tid+512] = __float2bfloat16((v2-mu)*rs*lw[tid+512] + lb[tid+512]);
}

// ---- bf16 MFMA GEMM, NT (C[M,N] = A[M,K] * B[N,K]^T), m97-style ----
template<int N, int K, bool RESID>
__device__ __forceinline__ void gemm_body(const bf16* __restrict__ A, const bf16* __restrict__ B,
                                          float* __restrict__ C, const float* __restrict__ resid){
  __shared__ __align__(16) bf16 As[128*32];
  __shared__ __align__(16) bf16 Bs[128*32];
  constexpr int NB = N/128;
  int bm = blockIdx.x / NB, bn = blockIdx.x % NB;
  int m0 = bm*128, n0 = bn*128;
  int tid = threadIdx.x, lane = tid&63, w = tid>>6;
  int wr = w>>1, wc = w&1;
  int lm = lane&15, kg = lane>>4;
  f32x4 acc[4][4];
  #pragma unroll
  for (int i=0;i<4;i++)
    #pragma unroll
    for (int j=0;j<4;j++) acc[i][j] = (f32x4){0.f,0.f,0.f,0.f};
  for (int kt=0; kt<K/32; ++kt){
    int k0 = kt*32;
    #pragma unroll
    for (int it=0; it<2; ++it){
      int sg = tid + it*256;                   // 512 16B segments per tile
      int row = sg>>2, ks = sg&3;
      gl_lds16(A + (size_t)(m0+row)*K + (k0+ks*8), (char*)As + sg*16);
      gl_lds16(B + (size_t)(n0+row)*K + (k0+ks*8), (char*)Bs + sg*16);
    }
    __syncthreads();                           // drains vmcnt -> tiles ready
    frag8 fa[4], fb[4];
    #pragma unroll
    for (int i=0;i<4;i++) fa[i] = *(const frag8*)(As + (wr*64+i*16+lm)*32 + kg*8);
    #pragma unroll
    for (int j=0;j<4;j++) fb[j] = *(const frag8*)(Bs + (wc*64+j*16+lm)*32 + kg*8);
    #pragma unroll
    for (int i=0;i<4;i++)
      #pragma unroll
      for (int j=0;j<4;j++)
        acc[i][j] = __builtin_amdgcn_mfma_f32_16x16x32_bf16(fa[i], fb[j], acc[i][j], 0,0,0);
    __syncthreads();
  }
  #pragma unroll
  for (int i=0;i<4;i++){
    #pragma unroll
    for (int j=0;j<4;j++){
      int colg = n0 + wc*64 + j*16 + lm;
      #pragma unroll
      for (int r=0;r<4;r++){
        int rowg = m0 + wr*64 + i*16 + kg*4 + r;   // row=(lane>>4)*4+r (m89-verified)
        float v = acc[i][j][r];
        if constexpr (RESID) v += resid[(size_t)rowg*N + colg];
        C[(size_t)rowg*N + colg] = v;
      }
    }
  }
}
__global__ __launch_bounds__(256) void k_gemm1(){
  gemm_body<NPAD, DM, false>(g_u, g_Win, g_zx, nullptr);
}
__global__ __launch_bounds__(256) void k_gemm2(float* __restrict__ out, const float* __restrict__ x){
  gemm_body<DM, DI, true>(g_yn, g_Wout, out, x);
}

// ---- depthwise causal conv(4) + SiLU over xBC cols of zxbcdt ----
__global__ __launch_bounds__(256) void k_conv(const float* __restrict__ cw, const float* __restrict__ cbv){
  size_t idx = (size_t)blockIdx.x*256 + threadIdx.x;   // < BL*CONVD
  int c = (int)(idx % CONVD);
  size_t bt = idx / CONVD;
  int t = (int)(bt % LQ);
  size_t bb = bt / LQ;
  float acc = cbv[c];
  #pragma unroll
  for (int k=0;k<4;k++){
    int tt = t - 3 + k;
    if (tt >= 0) acc += g_zx[(bb*LQ + tt)*(size_t)NPAD + DI + c] * cw[c*4 + k];
  }
  g_xbc[idx] = silu_f(acc);
}

// ---- dt softplus + dA precompute, layout [b*NH+h][LQ] ----
__global__ __launch_bounds__(256) void k_dadt(const float* __restrict__ dtb, const float* __restrict__ alog){
  int idx = blockIdx.x*256 + threadIdx.x;      // < BQ*NH*LQ
  int t = idx % LQ, bh = idx / LQ;
  int h = bh % NH, bb = bh / NH;
  float raw = g_zx[(size_t)(bb*LQ + t)*NPAD + (DI + CONVD) + h] + dtb[h];
  float dt = (raw > 15.f) ? raw : log1pf(expf(raw));
  float A = -expf(alog[h]);
  g_dt[idx] = dt;
  g_dA[idx] = expf(dt * A);
}

// ---- SSM scan: one block per (b,h); state s[64][128] in regs (4p x 8n per thread) ----
__global__ __launch_bounds__(256) void k_scan(const float* __restrict__ Dp){
  __shared__ float bcb[2][CHUNK][256];   // B(0..127) | C(128..255) per step
  __shared__ float xb [2][CHUNK][64];
  __shared__ float zb [2][CHUNK][64];
  __shared__ float dab[2][CHUNK];
  __shared__ float dtb2[2][CHUNK];
  int bh = blockIdx.x;
  int bb = bh / NH, h = bh % NH;
  int tid = threadIdx.x;
  int pg = tid >> 4, ng = tid & 15;      // 16 p-groups x 16 n-groups
  float Dh = Dp[h];
  float s[4][8] = {};

  auto stage = [&](int c, int buf){
    size_t rb = (size_t)bb*LQ + (size_t)c*CHUNK;
    #pragma unroll
    for (int it=0; it<8; ++it){                      // B|C: 32 rows x 256 floats
      int sg = tid + it*256;
      int row = sg >> 6, c4 = sg & 63;
      gl_lds16(&g_xbc[(rb+row)*CONVD + DI + c4*4], &bcb[buf][row][c4*4]);
    }
    #pragma unroll
    for (int it=0; it<2; ++it){                      // x and z: 32 rows x 64 floats
      int sg = tid + it*256;
      int row = sg >> 4, c4 = sg & 15;
      gl_lds16(&g_xbc[(rb+row)*CONVD + h*HD + c4*4], &xb[buf][row][c4*4]);
      gl_lds16(&g_zx [(rb+row)*NPAD  + h*HD + c4*4], &zb[buf][row][c4*4]);
    }
    if (tid < CHUNK)                                  // wave0 lanes 0..31
      gl_lds4(&g_dA[(size_t)bh*LQ + c*CHUNK + tid], &dab[buf][tid]);
    if (tid >= 64 && tid < 64+CHUNK)                  // wave1 lanes 0..31
      gl_lds4(&g_dt[(size_t)bh*LQ + c*CHUNK + (tid-64)], &dtb2[buf][tid-64]);
  };

  stage(0, 0);
  for (int c = 0; c < LQ/CHUNK; ++c){
    __syncthreads();                      // drains staging of chunk c
    if (c+1 < LQ/CHUNK) stage(c+1, (c+1)&1);
    int cb = c & 1;
    #pragma unroll 4
    for (int i=0; i<CHUNK; ++i){
      float dA = dab[cb][i], dt = dtb2[cb][i];
      f32x4 xv  = *(const f32x4*)&xb[cb][i][pg*4];
      f32x4 vb0 = *(const f32x4*)&bcb[cb][i][ng*8];
      f32x4 vb1 = *(const f32x4*)&bcb[cb][i][ng*8+4];
      f32x4 vc0 = *(const f32x4*)&bcb[cb][i][128+ng*8];
      f32x4 vc1 = *(const f32x4*)&bcb[cb][i][128+ng*8+4];
      float acc[4];
      #pragma unroll
      for (int p=0;p<4;p++){
        float dbx = dt * xv[p];
        float a = 0.f;
        #pragma unroll
        for (int n=0;n<4;n++){ s[p][n]   = s[p][n]  *dA + dbx*vb0[n]; a += s[p][n]  *vc0[n]; }
        #pragma unroll
        for (int n=0;n<4;n++){ s[p][n+4] = s[p][n+4]*dA + dbx*vb1[n]; a += s[p][n+4]*vc1[n]; }
        acc[p] = a;
      }
      #pragma unroll
      for (int o=1;o<16;o<<=1){
        #pragma unroll
        for (int p=0;p<4;p++) acc[p] += __shfl_xor(acc[p], o);
      }
      if (ng == 0){
        f32x4 zv = *(const f32x4*)&zb[cb][i][pg*4];
        int t = c*CHUNK + i;
        f32x4 ov;
        #pragma unroll
        for (int p=0;p<4;p++){
          float y = acc[p] + Dh*xv[p];
          ov[p] = y * silu_f(zv[p]);
        }
        *(f32x4*)&g_xbc[(size_t)(bb*LQ + t)*CONVD + h*HD + pg*4] = ov;  // ygate overlays x-cols
      }
    }
  }
}

// ---- RMSNorm of gated y -> bf16 ----
__global__ __launch_bounds__(256) void k_rms(const float* __restrict__ nw){
  int r = blockIdx.x, tid = threadIdx.x;
  const float* yr = g_xbc + (size_t)r*CONVD;   // cols 0..1535 hold ygate
  float v[6]; float q = 0.f;
  #pragma unroll
  for (int i=0;i<6;i++){ v[i] = yr[tid + i*256]; q += v[i]*v[i]; }
  __shared__ float red[4];
  #pragma unroll
  for (int o=32;o>0;o>>=1) q += __shfl_down(q,o);
  if ((tid&63)==0) red[tid>>6] = q;
  __syncthreads();
  float qt = red[0]+red[1]+red[2]+red[3];
  float sc = rsqrtf(qt*(1.f/DI) + 1e-5f);
  bf16* dst = g_yn + (size_t)r*DI;
  #pragma unroll
  for (int i=0;i<6;i++) dst[tid + i*256] = __float2bfloat16(v[i]*sc*nw[tid + i*256]);
}

extern "C" void kernel_launch(void* const* d_in, const int* in_sizes, int n_in,
                              void* d_out, int out_size, void* d_ws, size_t ws_size,
                              hipStream_t stream){
  const float* x    = (const float*)d_in[0];
  const float* Win  = (const float*)d_in[1];
  const float* cw   = (const float*)d_in[2];
  const float* cbv  = (const float*)d_in[3];
  const float* dtb  = (const float*)d_in[4];
  const float* alog = (const float*)d_in[5];
  const float* Dv   = (const float*)d_in[6];
  const float* nw   = (const float*)d_in[7];
  const float* Wout = (const float*)d_in[8];
  const float* lnw  = (const float*)d_in[9];
  const float* lnb  = (const float*)d_in[10];
  float* out = (float*)d_out;

  k_castWin <<<(NPAD*DM)/256, 256, 0, stream>>>(Win);
  k_castWout<<<(DM*DI)/256,   256, 0, stream>>>(Wout);
  k_ln      <<<BL,            256, 0, stream>>>(x, lnw, lnb);
  k_gemm1   <<<(BL/128)*(NPAD/128), 256, 0, stream>>>();
  k_conv    <<<(int)(((size_t)BL*CONVD)/256), 256, 0, stream>>>(cw, cbv);
  k_dadt    <<<(BQ*NH*LQ)/256, 256, 0, stream>>>(dtb, alog);
  k_scan    <<<BQ*NH,         256, 0, stream>>>(Dv);
  k_rms     <<<BL,            256, 0, stream>>>(nw);
  k_gemm2   <<<(BL/128)*(DM/128), 256, 0, stream>>>(out, x);
}

// Round 3
// 1034.266 us; speedup vs baseline: 1.8934x; 1.8934x over previous
//
#include <hip/hip_runtime.h>
#include <hip/hip_bf16.h>
#include <math.h>

#define BQ 8
#define LQ 2048
#define DM 768
#define DI 1536
#define DS 128
#define NH 24
#define HD 64
#define CONVD 1792          // DI + 2*DS
#define NPROJ 3352          // 2*DI + 2*DS + NH
#define NPAD 3456           // NPROJ padded to 128
#define BL (BQ*LQ)          // 16384 tokens
#define QC 128              // SSD chunk length
#define NCH (LQ/QC)         // 16 chunks per sequence
#define SPAD 136            // padded LDS row stride (f16 elems) -> 272B rows, 16B aligned

using f32x4 = __attribute__((ext_vector_type(4))) float;
typedef _Float16 f16;
using hf8 = __attribute__((ext_vector_type(8))) _Float16;

// ---- static scratch (module-load allocated; fully rewritten every launch) ----
__device__ __align__(16) f16   g_u[(size_t)BL*DM];
__device__ __align__(16) f16   g_Win[(size_t)NPAD*DM];
__device__ __align__(16) float g_zx[(size_t)BL*NPAD];
__device__ __align__(16) float g_xbc[(size_t)BL*CONVD];   // conv+silu out; x cols later overlaid by gated y
__device__ __align__(16) float g_a[BQ*NH*LQ];             // dt*A (log-decay per step)
__device__ __align__(16) float g_dt[BQ*NH*LQ];
__device__ __align__(16) float g_acum[BQ*NH*NCH*QC];      // per-chunk inclusive cumsum of dt*A
__device__ __align__(16) float g_yintra[(size_t)BQ*NH*NCH*QC*HD];
__device__ __align__(16) float g_sadd[(size_t)BQ*NH*NCH*HD*DS];
__device__ __align__(16) f16   g_sprev[(size_t)BQ*NH*NCH*HD*DS];
__device__ __align__(16) f16   g_yn[(size_t)BL*DI];
__device__ __align__(16) f16   g_Wout[(size_t)DM*DI];

__device__ __forceinline__ void gl_lds16(const void* g, void* l){
  __builtin_amdgcn_global_load_lds((const __attribute__((address_space(1))) unsigned int*)g,
                                   (__attribute__((address_space(3))) unsigned int*)l, 16, 0, 0);
}
__device__ __forceinline__ float silu_f(float v){ return v / (1.f + expf(-v)); }

// ---- weight casts ----
__global__ __launch_bounds__(256) void k_castWin(const float* __restrict__ W){
  int idx = blockIdx.x*256 + threadIdx.x;
  int row = idx / DM, col = idx % DM;
  float v = (row < NPROJ) ? W[(size_t)row*DM + col] : 0.f;
  g_Win[idx] = (f16)v;
}
__global__ __launch_bounds__(256) void k_castWout(const float* __restrict__ W){
  int idx = blockIdx.x*256 + threadIdx.x;
  g_Wout[idx] = (f16)W[idx];
}

// ---- LayerNorm -> f16 u ----
__global__ __launch_bounds__(256) void k_ln(const float* __restrict__ x,
                                            const float* __restrict__ lw,
                                            const float* __restrict__ lb){
  int r = blockIdx.x, tid = threadIdx.x;
  const float* xr = x + (size_t)r*DM;
  float v0 = xr[tid], v1 = xr[tid+256], v2 = xr[tid+512];
  float s = v0+v1+v2, q = v0*v0 + v1*v1 + v2*v2;
  __shared__ float red[8];
  #pragma unroll
  for (int o=32;o>0;o>>=1){ s += __shfl_down(s,o); q += __shfl_down(q,o); }
  if ((tid&63)==0){ red[tid>>6] = s; red[4+(tid>>6)] = q; }
  __syncthreads();
  float st = red[0]+red[1]+red[2]+red[3];
  float qt = red[4]+red[5]+red[6]+red[7];
  float mu = st * (1.f/DM);
  float var = qt * (1.f/DM) - mu*mu;
  float rs = rsqrtf(var + 1e-5f);
  f16* ur = g_u + (size_t)r*DM;
  ur[tid]     = (f16)((v0-mu)*rs*lw[tid]     + lb[tid]);
  ur[tid+256] = (f16)((v1-mu)*rs*lw[tid+256] + lb[tid+256]);
  ur[tid+512] = (f16)((v2-mu)*rs*lw[tid+512] + lb[tid+512]);
}

// ---- f16 MFMA GEMM, NT (C[M,N] = A[M,K] * B[N,K]^T), m97-style ----
template<int N, int K, bool RESID>
__device__ __forceinline__ void gemm_body(const f16* __restrict__ A, const f16* __restrict__ B,
                                          float* __restrict__ C, const float* __restrict__ resid){
  __shared__ __align__(16) f16 As[128*32];
  __shared__ __align__(16) f16 Bs[128*32];
  constexpr int NB = N/128;
  int bm = blockIdx.x / NB, bn = blockIdx.x % NB;
  int m0 = bm*128, n0 = bn*128;
  int tid = threadIdx.x, lane = tid&63, w = tid>>6;
  int wr = w>>1, wc = w&1;
  int lm = lane&15, kg = lane>>4;
  f32x4 acc[4][4];
  #pragma unroll
  for (int i=0;i<4;i++)
    #pragma unroll
    for (int j=0;j<4;j++) acc[i][j] = (f32x4){0.f,0.f,0.f,0.f};
  for (int kt=0; kt<K/32; ++kt){
    int k0 = kt*32;
    #pragma unroll
    for (int it=0; it<2; ++it){
      int sg = tid + it*256;
      int row = sg>>2, ks = sg&3;
      gl_lds16(A + (size_t)(m0+row)*K + (k0+ks*8), (char*)As + sg*16);
      gl_lds16(B + (size_t)(n0+row)*K + (k0+ks*8), (char*)Bs + sg*16);
    }
    __syncthreads();
    hf8 fa[4], fb[4];
    #pragma unroll
    for (int i=0;i<4;i++) fa[i] = *(const hf8*)(As + (wr*64+i*16+lm)*32 + kg*8);
    #pragma unroll
    for (int j=0;j<4;j++) fb[j] = *(const hf8*)(Bs + (wc*64+j*16+lm)*32 + kg*8);
    #pragma unroll
    for (int i=0;i<4;i++)
      #pragma unroll
      for (int j=0;j<4;j++)
        acc[i][j] = __builtin_amdgcn_mfma_f32_16x16x32_f16(fa[i], fb[j], acc[i][j], 0,0,0);
    __syncthreads();
  }
  #pragma unroll
  for (int i=0;i<4;i++){
    #pragma unroll
    for (int j=0;j<4;j++){
      int colg = n0 + wc*64 + j*16 + lm;
      #pragma unroll
      for (int r=0;r<4;r++){
        int rowg = m0 + wr*64 + i*16 + kg*4 + r;
        float v = acc[i][j][r];
        if constexpr (RESID) v += resid[(size_t)rowg*N + colg];
        C[(size_t)rowg*N + colg] = v;
      }
    }
  }
}
__global__ __launch_bounds__(256) void k_gemm1(){
  gemm_body<NPAD, DM, false>(g_u, g_Win, g_zx, nullptr);
}
__global__ __launch_bounds__(256) void k_gemm2(float* __restrict__ out, const float* __restrict__ x){
  gemm_body<DM, DI, true>(g_yn, g_Wout, out, x);
}

// ---- depthwise causal conv(4) + SiLU ----
__global__ __launch_bounds__(256) void k_conv(const float* __restrict__ cw, const float* __restrict__ cbv){
  size_t idx = (size_t)blockIdx.x*256 + threadIdx.x;
  int c = (int)(idx % CONVD);
  size_t bt = idx / CONVD;
  int t = (int)(bt % LQ);
  size_t bb = bt / LQ;
  float acc = cbv[c];
  #pragma unroll
  for (int k=0;k<4;k++){
    int tt = t - 3 + k;
    if (tt >= 0) acc += g_zx[(bb*LQ + tt)*(size_t)NPAD + DI + c] * cw[c*4 + k];
  }
  g_xbc[idx] = silu_f(acc);
}

// ---- dt softplus + log-decay a = dt*A ----
__global__ __launch_bounds__(256) void k_dadt(const float* __restrict__ dtb, const float* __restrict__ alog){
  int idx = blockIdx.x*256 + threadIdx.x;
  int t = idx % LQ, bh = idx / LQ;
  int h = bh % NH, bb = bh / NH;
  float raw = g_zx[(size_t)(bb*LQ + t)*NPAD + (DI + CONVD) + h] + dtb[h];
  float dt = (raw > 15.f) ? raw : log1pf(expf(raw));
  float A = -expf(alog[h]);
  g_dt[idx] = dt;
  g_a[idx] = dt * A;
}

// ---- SSD phase A: per (b,h,chunk): Acum, G=C@B^T, M=mask(G), Y_intra=M@Xdt, S_add=Xw^T@B ----
__global__ __launch_bounds__(256) void k_ssd_a(){
  __shared__ __align__(16) f16 CsMs[QC*SPAD];   // C tile, then reused for masked M
  __shared__ __align__(16) f16 Bs[QC*SPAD];     // B[t][n]
  __shared__ __align__(16) f16 Btw[DS*SPAD];    // B^T scaled: [n][t] * w_t
  __shared__ __align__(16) f16 Xt[HD*SPAD];     // (dt*x)^T : [p][t]
  __shared__ double Acd[QC];
  __shared__ float Ac[QC];
  __shared__ float Dts[QC];

  int blk = blockIdx.x;
  int h = blk % NH; int bc = blk / NH;
  int c = bc % NCH; int bb = bc / NCH;
  int bh = bb*NH + h;
  int tid = threadIdx.x, lane = tid&63, w = tid>>6;
  size_t rb = (size_t)bb*LQ + (size_t)c*QC;
  size_t ab = (size_t)bh*LQ + (size_t)c*QC;

  // Acum: inclusive prefix sum of a over the chunk (double for cancellation safety)
  if (tid < QC){
    double av = (double)g_a[ab + tid];
    #pragma unroll
    for (int o=1;o<64;o<<=1){
      double nv = __shfl_up(av, o);
      if (lane >= o) av += nv;
    }
    Acd[tid] = av;
    Dts[tid] = g_dt[ab + tid];
  }
  __syncthreads();
  if (tid < QC){
    float ff = (float)(Acd[tid] + (tid >= 64 ? Acd[63] : 0.0));
    Ac[tid] = ff;
    g_acum[((size_t)bh*NCH + c)*QC + tid] = ff;
  }
  __syncthreads();
  float Alast = Ac[QC-1];

  // stage B, C (row-major) and Btw (transposed, decay-weighted)
  #pragma unroll
  for (int it=0; it<16; ++it){
    int sg = tid + it*256;              // [0,4096)
    int row = sg>>5, cg = sg&31;
    const float* src = &g_xbc[(rb+row)*CONVD + DI + cg*4];
    f32x4 vb = *(const f32x4*)src;
    f32x4 vc = *(const f32x4*)(src + DS);
    float wrow = expf(Alast - Ac[row]);
    f16 tb[4], tc[4];
    #pragma unroll
    for (int k2=0;k2<4;k2++){ tb[k2]=(f16)vb[k2]; tc[k2]=(f16)vc[k2]; }
    *(uint2*)&Bs[row*SPAD + cg*4]   = *(uint2*)tb;
    *(uint2*)&CsMs[row*SPAD + cg*4] = *(uint2*)tc;
    #pragma unroll
    for (int k2=0;k2<4;k2++) Btw[(cg*4+k2)*SPAD + row] = (f16)(vb[k2]*wrow);
  }
  // stage Xt = (dt*x)^T
  #pragma unroll
  for (int it=0; it<8; ++it){
    int sg = tid + it*256;              // [0,2048)
    int row = sg>>4, cg = sg&15;
    f32x4 xv = *(const f32x4*)&g_xbc[(rb+row)*CONVD + h*HD + cg*4];
    float dtr = Dts[row];
    #pragma unroll
    for (int k2=0;k2<4;k2++) Xt[(cg*4+k2)*SPAD + row] = (f16)(xv[k2]*dtr);
  }
  __syncthreads();

  int wr = w>>1, wc = w&1, lm = lane&15, kg = lane>>4;

  // G = C @ B^T  (128x128, K=128)
  f32x4 acc[4][4];
  #pragma unroll
  for (int i=0;i<4;i++)
    #pragma unroll
    for (int j=0;j<4;j++) acc[i][j] = (f32x4){0.f,0.f,0.f,0.f};
  #pragma unroll
  for (int kk=0; kk<4; ++kk){
    hf8 fa[4], fb[4];
    #pragma unroll
    for (int i=0;i<4;i++) fa[i] = *(const hf8*)&CsMs[(wr*64+i*16+lm)*SPAD + kk*32 + kg*8];
    #pragma unroll
    for (int j=0;j<4;j++) fb[j] = *(const hf8*)&Bs[(wc*64+j*16+lm)*SPAD + kk*32 + kg*8];
    #pragma unroll
    for (int i=0;i<4;i++)
      #pragma unroll
      for (int j=0;j<4;j++)
        acc[i][j] = __builtin_amdgcn_mfma_f32_16x16x32_f16(fa[i], fb[j], acc[i][j], 0,0,0);
  }
  __syncthreads();                       // done reading C tile

  // M = causal-masked, decayed G -> CsMs (f16)
  #pragma unroll
  for (int it=0;it<4;it++){
    #pragma unroll
    for (int jt=0;jt<4;jt++){
      int j_ = wc*64 + jt*16 + lm;
      float aj = Ac[j_];
      #pragma unroll
      for (int r=0;r<4;r++){
        int i_ = wr*64 + it*16 + kg*4 + r;
        float m = (j_ <= i_) ? acc[it][jt][r] * expf(Ac[i_] - aj) : 0.f;
        CsMs[i_*SPAD + j_] = (f16)m;
      }
    }
  }
  __syncthreads();

  // Y_intra = M @ Xt^T  (128 x 64, K=128)
  f32x4 acc2[4][2];
  #pragma unroll
  for (int i=0;i<4;i++){ acc2[i][0]=(f32x4){0,0,0,0}; acc2[i][1]=(f32x4){0,0,0,0}; }
  #pragma unroll
  for (int kk=0; kk<4; ++kk){
    hf8 fa[4], fb[2];
    #pragma unroll
    for (int i=0;i<4;i++) fa[i] = *(const hf8*)&CsMs[(wr*64+i*16+lm)*SPAD + kk*32 + kg*8];
    #pragma unroll
    for (int j=0;j<2;j++) fb[j] = *(const hf8*)&Xt[(wc*32+j*16+lm)*SPAD + kk*32 + kg*8];
    #pragma unroll
    for (int i=0;i<4;i++)
      #pragma unroll
      for (int j=0;j<2;j++)
        acc2[i][j] = __builtin_amdgcn_mfma_f32_16x16x32_f16(fa[i], fb[j], acc2[i][j], 0,0,0);
  }
  size_t yb = ((size_t)bh*NCH + c)*QC*HD;
  #pragma unroll
  for (int it=0;it<4;it++)
    #pragma unroll
    for (int jt=0;jt<2;jt++){
      int p_ = wc*32 + jt*16 + lm;
      #pragma unroll
      for (int r=0;r<4;r++){
        int i_ = wr*64 + it*16 + kg*4 + r;
        g_yintra[yb + (size_t)i_*HD + p_] = acc2[it][jt][r];
      }
    }

  // S_add = Xt @ Btw^T  (64 x 128, K=128)
  f32x4 acc3[2][4];
  #pragma unroll
  for (int j=0;j<4;j++){ acc3[0][j]=(f32x4){0,0,0,0}; acc3[1][j]=(f32x4){0,0,0,0}; }
  #pragma unroll
  for (int kk=0; kk<4; ++kk){
    hf8 fa[2], fb[4];
    #pragma unroll
    for (int i=0;i<2;i++) fa[i] = *(const hf8*)&Xt[(wr*32+i*16+lm)*SPAD + kk*32 + kg*8];
    #pragma unroll
    for (int j=0;j<4;j++) fb[j] = *(const hf8*)&Btw[(wc*64+j*16+lm)*SPAD + kk*32 + kg*8];
    #pragma unroll
    for (int i=0;i<2;i++)
      #pragma unroll
      for (int j=0;j<4;j++)
        acc3[i][j] = __builtin_amdgcn_mfma_f32_16x16x32_f16(fa[i], fb[j], acc3[i][j], 0,0,0);
  }
  size_t sb = ((size_t)bh*NCH + c)*HD*DS;
  #pragma unroll
  for (int it=0;it<2;it++)
    #pragma unroll
    for (int jt=0;jt<4;jt++){
      int n_ = wc*64 + jt*16 + lm;
      #pragma unroll
      for (int r=0;r<4;r++){
        int p_ = wr*32 + it*16 + kg*4 + r;
        g_sadd[sb + (size_t)p_*DS + n_] = acc3[it][jt][r];
      }
    }
}

// ---- SSD phase B: inter-chunk state recurrence (16 serial steps, elementwise) ----
__global__ __launch_bounds__(256) void k_ssd_b(){
  int bh = blockIdx.x >> 5;
  int pn = (blockIdx.x & 31)*256 + threadIdx.x;
  float s = 0.f;
  size_t base = (size_t)bh*NCH;
  for (int c=0;c<NCH;c++){
    size_t o = (base + c)*(HD*DS) + pn;
    g_sprev[o] = (f16)s;
    float T = expf(g_acum[(base + c)*QC + (QC-1)]);
    s = s*T + g_sadd[o];
  }
}

// ---- SSD phase C: Y = Y_intra + (e*C)@s_prev^T + D*x; gate; write ygate ----
__global__ __launch_bounds__(256) void k_ssd_c(const float* __restrict__ Dp){
  __shared__ __align__(16) f16 Csc[QC*SPAD];
  __shared__ __align__(16) f16 Sp[HD*SPAD];
  __shared__ float Ex[QC];
  int blk = blockIdx.x;
  int h = blk % NH; int bc = blk / NH;
  int c = bc % NCH; int bb = bc / NCH;
  int bh = bb*NH + h;
  int tid = threadIdx.x, lane = tid&63, w = tid>>6;
  int wr = w>>1, wc = w&1, lm = lane&15, kg = lane>>4;
  size_t rb = (size_t)bb*LQ + (size_t)c*QC;
  if (tid < QC) Ex[tid] = expf(g_acum[((size_t)bh*NCH + c)*QC + tid]);
  __syncthreads();
  #pragma unroll
  for (int it=0; it<16; ++it){
    int sg = tid + it*256;
    int row = sg>>5, cg = sg&31;
    f32x4 vc = *(const f32x4*)&g_xbc[(rb+row)*CONVD + DI+DS + cg*4];
    float e = Ex[row];
    f16 tc[4];
    #pragma unroll
    for (int k2=0;k2<4;k2++) tc[k2] = (f16)(vc[k2]*e);
    *(uint2*)&Csc[row*SPAD + cg*4] = *(uint2*)tc;
  }
  const f16* sp = &g_sprev[((size_t)bh*NCH + c)*HD*DS];
  #pragma unroll
  for (int it=0; it<4; ++it){
    int sg = tid + it*256;
    int row = sg>>4, cg = sg&15;
    *(hf8*)&Sp[row*SPAD + cg*8] = *(const hf8*)(sp + row*DS + cg*8);
  }
  __syncthreads();
  f32x4 acc[4][2];
  #pragma unroll
  for (int i=0;i<4;i++){ acc[i][0]=(f32x4){0,0,0,0}; acc[i][1]=(f32x4){0,0,0,0}; }
  #pragma unroll
  for (int kk=0; kk<4; ++kk){
    hf8 fa[4], fb[2];
    #pragma unroll
    for (int i=0;i<4;i++) fa[i] = *(const hf8*)&Csc[(wr*64+i*16+lm)*SPAD + kk*32 + kg*8];
    #pragma unroll
    for (int j=0;j<2;j++) fb[j] = *(const hf8*)&Sp[(wc*32+j*16+lm)*SPAD + kk*32 + kg*8];
    #pragma unroll
    for (int i=0;i<4;i++)
      #pragma unroll
      for (int j=0;j<2;j++)
        acc[i][j] = __builtin_amdgcn_mfma_f32_16x16x32_f16(fa[i], fb[j], acc[i][j], 0,0,0);
  }
  float Dh = Dp[h];
  size_t yb = ((size_t)bh*NCH + c)*QC*HD;
  #pragma unroll
  for (int it=0;it<4;it++)
    #pragma unroll
    for (int jt=0;jt<2;jt++){
      int p_ = wc*32 + jt*16 + lm;
      #pragma unroll
      for (int r=0;r<4;r++){
        int i_ = wr*64 + it*16 + kg*4 + r;
        size_t t = rb + i_;
        float xv = g_xbc[t*CONVD + h*HD + p_];
        float zv = g_zx [t*NPAD  + h*HD + p_];
        float y = acc[it][jt][r] + g_yintra[yb + (size_t)i_*HD + p_] + Dh*xv;
        g_xbc[t*CONVD + h*HD + p_] = y * silu_f(zv);
      }
    }
}

// ---- RMSNorm of gated y -> f16 ----
__global__ __launch_bounds__(256) void k_rms(const float* __restrict__ nw){
  int r = blockIdx.x, tid = threadIdx.x;
  const float* yr = g_xbc + (size_t)r*CONVD;
  float v[6]; float q = 0.f;
  #pragma unroll
  for (int i=0;i<6;i++){ v[i] = yr[tid + i*256]; q += v[i]*v[i]; }
  __shared__ float red[4];
  #pragma unroll
  for (int o=32;o>0;o>>=1) q += __shfl_down(q,o);
  if ((tid&63)==0) red[tid>>6] = q;
  __syncthreads();
  float qt = red[0]+red[1]+red[2]+red[3];
  float sc = rsqrtf(qt*(1.f/DI) + 1e-5f);
  f16* dst = g_yn + (size_t)r*DI;
  #pragma unroll
  for (int i=0;i<6;i++) dst[tid + i*256] = (f16)(v[i]*sc*nw[tid + i*256]);
}

extern "C" void kernel_launch(void* const* d_in, const int* in_sizes, int n_in,
                              void* d_out, int out_size, void* d_ws, size_t ws_size,
                              hipStream_t stream){
  const float* x    = (const float*)d_in[0];
  const float* Win  = (const float*)d_in[1];
  const float* cw   = (const float*)d_in[2];
  const float* cbv  = (const float*)d_in[3];
  const float* dtb  = (const float*)d_in[4];
  const float* alog = (const float*)d_in[5];
  const float* Dv   = (const float*)d_in[6];
  const float* nw   = (const float*)d_in[7];
  const float* Wout = (const float*)d_in[8];
  const float* lnw  = (const float*)d_in[9];
  const float* lnb  = (const float*)d_in[10];
  float* out = (float*)d_out;

  k_castWin <<<(NPAD*DM)/256, 256, 0, stream>>>(Win);
  k_castWout<<<(DM*DI)/256,   256, 0, stream>>>(Wout);
  k_ln      <<<BL,            256, 0, stream>>>(x, lnw, lnb);
  k_gemm1   <<<(BL/128)*(NPAD/128), 256, 0, stream>>>();
  k_conv    <<<(int)(((size_t)BL*CONVD)/256), 256, 0, stream>>>(cw, cbv);
  k_dadt    <<<(BQ*NH*LQ)/256, 256, 0, stream>>>(dtb, alog);
  k_ssd_a   <<<BQ*NCH*NH,     256, 0, stream>>>();
  k_ssd_b   <<<BQ*NH*32,      256, 0, stream>>>();
  k_ssd_c   <<<BQ*NCH*NH,     256, 0, stream>>>(Dv);
  k_rms     <<<BL,            256, 0, stream>>>(nw);
  k_gemm2   <<<(BL/128)*(DM/128), 256, 0, stream>>>(out, x);
}

// Round 4
// 916.216 us; speedup vs baseline: 2.1374x; 1.1288x over previous
//
#include <hip/hip_runtime.h>
#include <hip/hip_bf16.h>
#include <math.h>

#define BQ 8
#define LQ 2048
#define DM 768
#define DI 1536
#define DS 128
#define NH 24
#define HD 64
#define CONVD 1792          // DI + 2*DS
#define NPROJ 3352          // 2*DI + 2*DS + NH
#define NPAD 3456           // NPROJ padded to 128
#define BL (BQ*LQ)          // 16384 tokens
#define QC 128              // SSD chunk length
#define NCH (LQ/QC)         // 16 chunks per sequence
#define SPAD2 136           // padded LDS row stride for ssd_c (f16)

using f32x4 = __attribute__((ext_vector_type(4))) float;
typedef _Float16 f16;
using hf8 = __attribute__((ext_vector_type(8))) _Float16;
using hf4 = __attribute__((ext_vector_type(4))) _Float16;

// ---- static scratch ----
__device__ __align__(16) f16   g_u[(size_t)BL*DM];
__device__ __align__(16) f16   g_Win[(size_t)NPAD*DM];
__device__ __align__(16) f16   g_zx[(size_t)BL*NPAD];       // zxbcdt f16
__device__ __align__(16) float g_dtraw[(size_t)NH*BL];      // [h][b*t] raw dt cols f32
__device__ __align__(16) f16   g_xbc[(size_t)BL*CONVD];     // conv+silu; x cols overlaid by gated y
__device__ __align__(16) float g_a[BQ*NH*LQ];
__device__ __align__(16) float g_dt[BQ*NH*LQ];
__device__ __align__(16) float g_acum[BQ*NH*NCH*QC];
__device__ __align__(16) f16   g_G[(size_t)BQ*NCH*QC*QC];   // C@B^T per (b,c)
__device__ __align__(16) f16   g_yintra[(size_t)BQ*NH*NCH*HD*QC];  // [bh][c][p][t]
__device__ __align__(16) float g_sadd[(size_t)BQ*NH*NCH*HD*DS];
__device__ __align__(16) f16   g_sprev[(size_t)BQ*NH*NCH*HD*DS];
__device__ __align__(16) f16   g_yn[(size_t)BL*DI];
__device__ __align__(16) f16   g_Wout[(size_t)DM*DI];

__device__ __forceinline__ void gl_lds16(const void* g, void* l){
  __builtin_amdgcn_global_load_lds((const __attribute__((address_space(1))) unsigned int*)g,
                                   (__attribute__((address_space(3))) unsigned int*)l, 16, 0, 0);
}
__device__ __forceinline__ float silu_f(float v){ return v / (1.f + expf(-v)); }
__device__ __forceinline__ int swz(int row, int blk){ return blk ^ ((row ^ (row>>3)) & 15); }

// ---- weight casts ----
__global__ __launch_bounds__(256) void k_castWin(const float* __restrict__ W){
  int idx = blockIdx.x*256 + threadIdx.x;
  int row = idx / DM, col = idx % DM;
  float v = (row < NPROJ) ? W[(size_t)row*DM + col] : 0.f;
  g_Win[idx] = (f16)v;
}
__global__ __launch_bounds__(256) void k_castWout(const float* __restrict__ W){
  int idx = blockIdx.x*256 + threadIdx.x;
  g_Wout[idx] = (f16)W[idx];
}

// ---- LayerNorm -> f16 u ----
__global__ __launch_bounds__(256) void k_ln(const float* __restrict__ x,
                                            const float* __restrict__ lw,
                                            const float* __restrict__ lb){
  int r = blockIdx.x, tid = threadIdx.x;
  const float* xr = x + (size_t)r*DM;
  float v0 = xr[tid], v1 = xr[tid+256], v2 = xr[tid+512];
  float s = v0+v1+v2, q = v0*v0 + v1*v1 + v2*v2;
  __shared__ float red[8];
  #pragma unroll
  for (int o=32;o>0;o>>=1){ s += __shfl_down(s,o); q += __shfl_down(q,o); }
  if ((tid&63)==0){ red[tid>>6] = s; red[4+(tid>>6)] = q; }
  __syncthreads();
  float st = red[0]+red[1]+red[2]+red[3];
  float qt = red[4]+red[5]+red[6]+red[7];
  float mu = st * (1.f/DM);
  float var = qt * (1.f/DM) - mu*mu;
  float rs = rsqrtf(var + 1e-5f);
  f16* ur = g_u + (size_t)r*DM;
  ur[tid]     = (f16)((v0-mu)*rs*lw[tid]     + lb[tid]);
  ur[tid+256] = (f16)((v1-mu)*rs*lw[tid+256] + lb[tid+256]);
  ur[tid+512] = (f16)((v2-mu)*rs*lw[tid+512] + lb[tid+512]);
}

// ---- f16 MFMA GEMM, NT. MODE 0: -> g_zx f16 (+f32 dt cols). MODE 1: -> f32 out + resid ----
template<int N, int K, int MODE>
__device__ __forceinline__ void gemm_body(const f16* __restrict__ A, const f16* __restrict__ B,
                                          float* __restrict__ C, const float* __restrict__ resid){
  __shared__ __align__(16) f16 As[128*32];
  __shared__ __align__(16) f16 Bs[128*32];
  constexpr int NB = N/128;
  int bm = blockIdx.x / NB, bn = blockIdx.x % NB;
  int m0 = bm*128, n0 = bn*128;
  int tid = threadIdx.x, lane = tid&63, w = tid>>6;
  int wr = w>>1, wc = w&1;
  int lm = lane&15, kg = lane>>4;
  f32x4 acc[4][4];
  #pragma unroll
  for (int i=0;i<4;i++)
    #pragma unroll
    for (int j=0;j<4;j++) acc[i][j] = (f32x4){0.f,0.f,0.f,0.f};
  for (int kt=0; kt<K/32; ++kt){
    int k0 = kt*32;
    #pragma unroll
    for (int it=0; it<2; ++it){
      int sg = tid + it*256;
      int row = sg>>2, ks = sg&3;
      gl_lds16(A + (size_t)(m0+row)*K + (k0+ks*8), (char*)As + sg*16);
      gl_lds16(B + (size_t)(n0+row)*K + (k0+ks*8), (char*)Bs + sg*16);
    }
    __syncthreads();
    hf8 fa[4], fb[4];
    #pragma unroll
    for (int i=0;i<4;i++) fa[i] = *(const hf8*)(As + (wr*64+i*16+lm)*32 + kg*8);
    #pragma unroll
    for (int j=0;j<4;j++) fb[j] = *(const hf8*)(Bs + (wc*64+j*16+lm)*32 + kg*8);
    #pragma unroll
    for (int i=0;i<4;i++)
      #pragma unroll
      for (int j=0;j<4;j++)
        acc[i][j] = __builtin_amdgcn_mfma_f32_16x16x32_f16(fa[i], fb[j], acc[i][j], 0,0,0);
    __syncthreads();
  }
  #pragma unroll
  for (int i=0;i<4;i++){
    #pragma unroll
    for (int j=0;j<4;j++){
      int colg = n0 + wc*64 + j*16 + lm;
      #pragma unroll
      for (int r=0;r<4;r++){
        int rowg = m0 + wr*64 + i*16 + kg*4 + r;
        float v = acc[i][j][r];
        if constexpr (MODE == 0){
          g_zx[(size_t)rowg*NPAD + colg] = (f16)v;
          if (colg >= DI+CONVD && colg < NPROJ)
            g_dtraw[(size_t)(colg-(DI+CONVD))*BL + rowg] = v;
        } else {
          C[(size_t)rowg*N + colg] = v + resid[(size_t)rowg*N + colg];
        }
      }
    }
  }
}
__global__ __launch_bounds__(256) void k_gemm1(){
  gemm_body<NPAD, DM, 0>(g_u, g_Win, nullptr, nullptr);
}
__global__ __launch_bounds__(256) void k_gemm2(float* __restrict__ out, const float* __restrict__ x){
  gemm_body<DM, DI, 1>(g_yn, g_Wout, out, x);
}

// ---- depthwise causal conv(4) + SiLU, 8 channels/thread ----
__global__ __launch_bounds__(256) void k_conv(const float* __restrict__ cw, const float* __restrict__ cbv){
  int idx = blockIdx.x*256 + threadIdx.x;     // < BL*CONVD/8
  int c8 = idx % (CONVD/8);
  int bt = idx / (CONVD/8);
  int t = bt % LQ;
  int c0 = c8*8;
  float acc[8];
  #pragma unroll
  for (int e=0;e<8;e++) acc[e] = cbv[c0+e];
  #pragma unroll
  for (int k=0;k<4;k++){
    int tt = t - 3 + k;
    if (tt >= 0){
      hf8 v = *(const hf8*)&g_zx[(size_t)(bt-3+k)*NPAD + DI + c0];
      #pragma unroll
      for (int e=0;e<8;e++) acc[e] += (float)v[e] * cw[(c0+e)*4 + k];
    }
  }
  f16 ov[8];
  #pragma unroll
  for (int e=0;e<8;e++) ov[e] = (f16)silu_f(acc[e]);
  *(hf8*)&g_xbc[(size_t)bt*CONVD + c0] = *(hf8*)ov;
}

// ---- dt softplus + log-decay a = dt*A ----
__global__ __launch_bounds__(256) void k_dadt(const float* __restrict__ dtb, const float* __restrict__ alog){
  int idx = blockIdx.x*256 + threadIdx.x;
  int t = idx % LQ, bh = idx / LQ;
  int h = bh % NH, bb = bh / NH;
  float raw = g_dtraw[(size_t)h*BL + bb*LQ + t] + dtb[h];
  float dt = (raw > 15.f) ? raw : log1pf(expf(raw));
  float A = -expf(alog[h]);
  g_dt[idx] = dt;
  g_a[idx] = dt * A;
}

// ---- G = C @ B^T per (b,c), head-independent ----
__global__ __launch_bounds__(256) void k_gpre(){
  __shared__ __align__(16) f16 Cs[QC*128];
  __shared__ __align__(16) f16 Bs[QC*128];
  int blk = blockIdx.x;            // bb*NCH + c
  int bb = blk / NCH, c = blk % NCH;
  size_t rb = (size_t)bb*LQ + (size_t)c*QC;
  int tid = threadIdx.x, lane = tid&63, w = tid>>6;
  #pragma unroll
  for (int it=0; it<8; ++it){
    int sg = tid + it*256;         // [0,2048)
    int t = sg>>4, nbd = sg&15;
    int nbs = swz(t, nbd);         // pre-swizzled source block
    gl_lds16(&g_xbc[(rb+t)*CONVD + DI    + nbs*8], (char*)Bs + sg*16);
    gl_lds16(&g_xbc[(rb+t)*CONVD + DI+DS + nbs*8], (char*)Cs + sg*16);
  }
  __syncthreads();
  int wr = w>>1, wc = w&1, lm = lane&15, kg = lane>>4;
  f32x4 acc[4][4];
  #pragma unroll
  for (int i=0;i<4;i++)
    #pragma unroll
    for (int j=0;j<4;j++) acc[i][j] = (f32x4){0.f,0.f,0.f,0.f};
  #pragma unroll
  for (int kk=0; kk<4; ++kk){
    hf8 fa[4], fb[4];
    #pragma unroll
    for (int i=0;i<4;i++){ int tc = wr*64+i*16+lm; fa[i] = *(const hf8*)&Cs[tc*128 + swz(tc, kk*4+kg)*8]; }
    #pragma unroll
    for (int j=0;j<4;j++){ int tb = wc*64+j*16+lm; fb[j] = *(const hf8*)&Bs[tb*128 + swz(tb, kk*4+kg)*8]; }
    #pragma unroll
    for (int i=0;i<4;i++)
      #pragma unroll
      for (int j=0;j<4;j++)
        acc[i][j] = __builtin_amdgcn_mfma_f32_16x16x32_f16(fa[i], fb[j], acc[i][j], 0,0,0);
  }
  f16* gdst = g_G + (size_t)blk*QC*128;
  #pragma unroll
  for (int i=0;i<4;i++)
    #pragma unroll
    for (int j=0;j<4;j++){
      int j_ = wc*64 + j*16 + lm;
      #pragma unroll
      for (int r=0;r<4;r++){
        int i_ = wr*64 + i*16 + kg*4 + r;
        gdst[(size_t)i_*128 + j_] = (f16)acc[i][j][r];
      }
    }
}

// ---- SSD phase A: per (b,h,c): Acum; M = G*decay; Y_intra = M@Xt^T; S_add = Xt@Btw^T ----
__global__ __launch_bounds__(512) void k_ssd_a(){
  __shared__ __align__(16) f16 Ms[QC*128];    // 32K, swizzled rows i
  __shared__ __align__(16) f16 Btw[DS*128];   // 32K, [n][t] swizzled
  __shared__ __align__(16) f16 Xt[HD*128];    // 16K, [p][t] swizzled
  __shared__ float Ac[QC];
  __shared__ float Dts[QC];
  __shared__ double dtot;
  int blk = blockIdx.x;
  int h = blk % NH; int bc = blk / NH;
  int c = bc % NCH; int bb = bc / NCH;
  int bh = bb*NH + h;
  int tid = threadIdx.x, lane = tid&63;
  size_t rb = (size_t)bb*LQ + (size_t)c*QC;
  size_t ab = (size_t)bh*LQ + (size_t)c*QC;

  double av = 0.0;
  if (tid < QC){
    av = (double)g_a[ab + tid];
    #pragma unroll
    for (int o=1;o<64;o<<=1){
      double nv = __shfl_up(av, o);
      if (lane >= o) av += nv;
    }
    if (tid == 63) dtot = av;
    Dts[tid] = g_dt[ab + tid];
  }
  __syncthreads();
  if (tid < QC){
    float ff = (float)(av + (tid >= 64 ? dtot : 0.0));
    Ac[tid] = ff;
    g_acum[((size_t)bh*NCH + c)*QC + tid] = ff;
  }
  __syncthreads();
  float Alast = Ac[QC-1];

  // stage Xt (threads 0..255) and Btw (threads 256..511)
  if (tid < 256){
    int pb = tid & 15, tb = tid >> 4;
    int p0 = pb*4, t0 = tb*8;
    f16 outv[4][8];
    #pragma unroll
    for (int r=0;r<8;r++){
      int t = t0 + r;
      hf4 xv = *(const hf4*)&g_xbc[(rb+t)*CONVD + h*HD + p0];
      float dtr = Dts[t];
      #pragma unroll
      for (int e=0;e<4;e++) outv[e][r] = (f16)((float)xv[e] * dtr);
    }
    #pragma unroll
    for (int e=0;e<4;e++){
      int p = p0 + e;
      *(hf8*)&Xt[p*128 + swz(p, tb)*8] = *(hf8*)outv[e];
    }
  } else {
    int tid2 = tid - 256;
    int nb = tid2 & 15, tb = tid2 >> 4;
    int n0 = nb*8, t0 = tb*8;
    f16 outv[8][8];
    #pragma unroll
    for (int r=0;r<8;r++){
      int t = t0 + r;
      hf8 bv = *(const hf8*)&g_xbc[(rb+t)*CONVD + DI + n0];
      float wr_ = expf(Alast - Ac[t]);
      #pragma unroll
      for (int e=0;e<8;e++) outv[e][r] = (f16)((float)bv[e] * wr_);
    }
    #pragma unroll
    for (int e=0;e<8;e++){
      int n = n0 + e;
      *(hf8*)&Btw[n*128 + swz(n, tb)*8] = *(hf8*)outv[e];
    }
  }
  // stage Ms = G * decay mask (all 512 threads: row i = tid>>2, 32 j's)
  {
    int i_ = tid >> 2;
    int j0 = (tid & 3) * 32;
    float ai = Ac[i_];
    const f16* gsrc = &g_G[(size_t)(bb*NCH + c)*QC*128 + (size_t)i_*128 + j0];
    #pragma unroll
    for (int u=0; u<4; ++u){
      hf8 gv = *(const hf8*)(gsrc + u*8);
      f16 mv[8];
      #pragma unroll
      for (int e=0;e<8;e++){
        int j = j0 + u*8 + e;
        float m = (j <= i_) ? (float)gv[e] * expf(ai - Ac[j]) : 0.f;
        mv[e] = (f16)m;
      }
      *(hf8*)&Ms[i_*128 + swz(i_, j0/8 + u)*8] = *(hf8*)mv;
    }
  }
  __syncthreads();

  int w = tid>>6, lm = lane&15, kg = lane>>4;

  // Y_intra = Ms @ Xt^T (128 x 64): waves 4x2
  {
    int wr = w>>1, wc = w&1;
    f32x4 acc2[2][2];
    #pragma unroll
    for (int i=0;i<2;i++){ acc2[i][0]=(f32x4){0,0,0,0}; acc2[i][1]=(f32x4){0,0,0,0}; }
    #pragma unroll
    for (int kk=0; kk<4; ++kk){
      hf8 fa[2], fb[2];
      #pragma unroll
      for (int ii=0;ii<2;ii++){ int i_ = wr*32+ii*16+lm; fa[ii] = *(const hf8*)&Ms[i_*128 + swz(i_, kk*4+kg)*8]; }
      #pragma unroll
      for (int jj=0;jj<2;jj++){ int p_ = wc*32+jj*16+lm; fb[jj] = *(const hf8*)&Xt[p_*128 + swz(p_, kk*4+kg)*8]; }
      #pragma unroll
      for (int ii=0;ii<2;ii++)
        #pragma unroll
        for (int jj=0;jj<2;jj++)
          acc2[ii][jj] = __builtin_amdgcn_mfma_f32_16x16x32_f16(fa[ii], fb[jj], acc2[ii][jj], 0,0,0);
    }
    size_t yb = ((size_t)bh*NCH + c)*(HD*QC);
    #pragma unroll
    for (int ii=0;ii<2;ii++)
      #pragma unroll
      for (int jj=0;jj<2;jj++){
        int p_ = wc*32 + jj*16 + lm;
        int i0 = wr*32 + ii*16 + kg*4;
        f16 vv[4];
        #pragma unroll
        for (int r=0;r<4;r++) vv[r] = (f16)acc2[ii][jj][r];
        *(hf4*)&g_yintra[yb + (size_t)p_*QC + i0] = *(hf4*)vv;
      }
  }
  // S_add = Xt @ Btw^T (64 x 128): waves 2x4
  {
    int wr = w>>2, wc = w&3;
    f32x4 acc3[2][2];
    #pragma unroll
    for (int i=0;i<2;i++){ acc3[i][0]=(f32x4){0,0,0,0}; acc3[i][1]=(f32x4){0,0,0,0}; }
    #pragma unroll
    for (int kk=0; kk<4; ++kk){
      hf8 fa[2], fb[2];
      #pragma unroll
      for (int ii=0;ii<2;ii++){ int p_ = wr*32+ii*16+lm; fa[ii] = *(const hf8*)&Xt[p_*128 + swz(p_, kk*4+kg)*8]; }
      #pragma unroll
      for (int jj=0;jj<2;jj++){ int n_ = wc*32+jj*16+lm; fb[jj] = *(const hf8*)&Btw[n_*128 + swz(n_, kk*4+kg)*8]; }
      #pragma unroll
      for (int ii=0;ii<2;ii++)
        #pragma unroll
        for (int jj=0;jj<2;jj++)
          acc3[ii][jj] = __builtin_amdgcn_mfma_f32_16x16x32_f16(fa[ii], fb[jj], acc3[ii][jj], 0,0,0);
    }
    size_t sb = ((size_t)bh*NCH + c)*HD*DS;
    #pragma unroll
    for (int ii=0;ii<2;ii++)
      #pragma unroll
      for (int jj=0;jj<2;jj++){
        int n_ = wc*32 + jj*16 + lm;
        #pragma unroll
        for (int r=0;r<4;r++){
          int p_ = wr*32 + ii*16 + kg*4 + r;
          g_sadd[sb + (size_t)p_*DS + n_] = acc3[ii][jj][r];
        }
      }
  }
}

// ---- SSD phase B: inter-chunk state recurrence ----
__global__ __launch_bounds__(256) void k_ssd_b(){
  int bh = blockIdx.x >> 5;
  int pn = (blockIdx.x & 31)*256 + threadIdx.x;
  float s = 0.f;
  size_t base = (size_t)bh*NCH;
  for (int c=0;c<NCH;c++){
    size_t o = (base + c)*(HD*DS) + pn;
    g_sprev[o] = (f16)s;
    float T = expf(g_acum[(base + c)*QC + (QC-1)]);
    s = s*T + g_sadd[o];
  }
}

// ---- SSD phase C: Y = Y_intra + (e*C)@s_prev^T + D*x; gate; write ygate ----
__global__ __launch_bounds__(256) void k_ssd_c(const float* __restrict__ Dp){
  __shared__ __align__(16) f16 Csc[QC*SPAD2];
  __shared__ __align__(16) f16 Sp[HD*SPAD2];
  __shared__ float Ex[QC];
  int blk = blockIdx.x;
  int h = blk % NH; int bc = blk / NH;
  int c = bc % NCH; int bb = bc / NCH;
  int bh = bb*NH + h;
  int tid = threadIdx.x, lane = tid&63, w = tid>>6;
  int wr = w>>1, wc = w&1, lm = lane&15, kg = lane>>4;
  size_t rb = (size_t)bb*LQ + (size_t)c*QC;
  if (tid < QC) Ex[tid] = expf(g_acum[((size_t)bh*NCH + c)*QC + tid]);
  __syncthreads();
  #pragma unroll
  for (int it=0; it<8; ++it){
    int sg = tid + it*256;            // [0,2048)
    int row = sg>>4, bk = sg&15;
    hf8 cv = *(const hf8*)&g_xbc[(rb+row)*CONVD + DI+DS + bk*8];
    float e = Ex[row];
    f16 tc[8];
    #pragma unroll
    for (int k2=0;k2<8;k2++) tc[k2] = (f16)((float)cv[k2]*e);
    *(hf8*)&Csc[row*SPAD2 + bk*8] = *(hf8*)tc;
  }
  const f16* sp = &g_sprev[((size_t)bh*NCH + c)*HD*DS];
  #pragma unroll
  for (int it=0; it<4; ++it){
    int sg = tid + it*256;            // [0,1024)
    int row = sg>>4, bk = sg&15;
    *(hf8*)&Sp[row*SPAD2 + bk*8] = *(const hf8*)(sp + row*DS + bk*8);
  }
  __syncthreads();
  f32x4 acc[4][2];
  #pragma unroll
  for (int i=0;i<4;i++){ acc[i][0]=(f32x4){0,0,0,0}; acc[i][1]=(f32x4){0,0,0,0}; }
  #pragma unroll
  for (int kk=0; kk<4; ++kk){
    hf8 fa[4], fb[2];
    #pragma unroll
    for (int i=0;i<4;i++) fa[i] = *(const hf8*)&Csc[(wr*64+i*16+lm)*SPAD2 + kk*32 + kg*8];
    #pragma unroll
    for (int j=0;j<2;j++) fb[j] = *(const hf8*)&Sp[(wc*32+j*16+lm)*SPAD2 + kk*32 + kg*8];
    #pragma unroll
    for (int i=0;i<4;i++)
      #pragma unroll
      for (int j=0;j<2;j++)
        acc[i][j] = __builtin_amdgcn_mfma_f32_16x16x32_f16(fa[i], fb[j], acc[i][j], 0,0,0);
  }
  float Dh = Dp[h];
  size_t yb = ((size_t)bh*NCH + c)*(HD*QC);
  #pragma unroll
  for (int it=0;it<4;it++)
    #pragma unroll
    for (int jt=0;jt<2;jt++){
      int p_ = wc*32 + jt*16 + lm;
      int i0 = wr*64 + it*16 + kg*4;
      hf4 yi = *(const hf4*)&g_yintra[yb + (size_t)p_*QC + i0];
      #pragma unroll
      for (int r=0;r<4;r++){
        int i_ = i0 + r;
        size_t t = rb + i_;
        float xv = (float)g_xbc[t*CONVD + h*HD + p_];
        float zv = (float)g_zx [t*NPAD  + h*HD + p_];
        float y = acc[it][jt][r] + (float)yi[r] + Dh*xv;
        g_xbc[t*CONVD + h*HD + p_] = (f16)(y * silu_f(zv));
      }
    }
}

// ---- RMSNorm of gated y -> f16 ----
__global__ __launch_bounds__(256) void k_rms(const float* __restrict__ nw){
  int r = blockIdx.x, tid = threadIdx.x;
  const f16* yr = g_xbc + (size_t)r*CONVD;
  float v[6]; float q = 0.f;
  #pragma unroll
  for (int i=0;i<6;i++){ v[i] = (float)yr[tid + i*256]; q += v[i]*v[i]; }
  __shared__ float red[4];
  #pragma unroll
  for (int o=32;o>0;o>>=1) q += __shfl_down(q,o);
  if ((tid&63)==0) red[tid>>6] = q;
  __syncthreads();
  float qt = red[0]+red[1]+red[2]+red[3];
  float sc = rsqrtf(qt*(1.f/DI) + 1e-5f);
  f16* dst = g_yn + (size_t)r*DI;
  #pragma unroll
  for (int i=0;i<6;i++) dst[tid + i*256] = (f16)(v[i]*sc*nw[tid + i*256]);
}

extern "C" void kernel_launch(void* const* d_in, const int* in_sizes, int n_in,
                              void* d_out, int out_size, void* d_ws, size_t ws_size,
                              hipStream_t stream){
  const float* x    = (const float*)d_in[0];
  const float* Win  = (const float*)d_in[1];
  const float* cw   = (const float*)d_in[2];
  const float* cbv  = (const float*)d_in[3];
  const float* dtb  = (const float*)d_in[4];
  const float* alog = (const float*)d_in[5];
  const float* Dv   = (const float*)d_in[6];
  const float* nw   = (const float*)d_in[7];
  const float* Wout = (const float*)d_in[8];
  const float* lnw  = (const float*)d_in[9];
  const float* lnb  = (const float*)d_in[10];
  float* out = (float*)d_out;

  k_castWin <<<(NPAD*DM)/256, 256, 0, stream>>>(Win);
  k_castWout<<<(DM*DI)/256,   256, 0, stream>>>(Wout);
  k_ln      <<<BL,            256, 0, stream>>>(x, lnw, lnb);
  k_gemm1   <<<(BL/128)*(NPAD/128), 256, 0, stream>>>();
  k_conv    <<<(BL*CONVD/8)/256, 256, 0, stream>>>(cw, cbv);
  k_dadt    <<<(BQ*NH*LQ)/256, 256, 0, stream>>>(dtb, alog);
  k_gpre    <<<BQ*NCH,        256, 0, stream>>>();
  k_ssd_a   <<<BQ*NCH*NH,     512, 0, stream>>>();
  k_ssd_b   <<<BQ*NH*32,      256, 0, stream>>>();
  k_ssd_c   <<<BQ*NCH*NH,     256, 0, stream>>>(Dv);
  k_rms     <<<BL,            256, 0, stream>>>(nw);
  k_gemm2   <<<(BL/128)*(DM/128), 256, 0, stream>>>(out, x);
}

// Round 5
// 731.581 us; speedup vs baseline: 2.6768x; 1.2524x over previous
//
#include <hip/hip_runtime.h>
#include <hip/hip_bf16.h>
#include <math.h>

#define BQ 8
#define LQ 2048
#define DM 768
#define DI 1536
#define DS 128
#define NH 24
#define HD 64
#define CONVD 1792          // DI + 2*DS
#define NPROJ 3352          // 2*DI + 2*DS + NH
#define NPAD 3456           // NPROJ padded to 128
#define BL (BQ*LQ)          // 16384 tokens
#define QC 128              // SSD chunk length
#define NCH (LQ/QC)         // 16 chunks per sequence
#define SPAD2 136           // padded LDS row stride for ssd_c (f16)

using f32x4 = __attribute__((ext_vector_type(4))) float;
typedef _Float16 f16;
using hf8 = __attribute__((ext_vector_type(8))) _Float16;
using hf4 = __attribute__((ext_vector_type(4))) _Float16;

// ---- static scratch ----
__device__ __align__(16) f16   g_u[(size_t)BL*DM];
__device__ __align__(16) f16   g_Win[(size_t)NPAD*DM];
__device__ __align__(16) f16   g_zx[(size_t)BL*NPAD];       // zxbcdt f16
__device__ __align__(16) float g_dtraw[(size_t)NH*BL];      // [h][b*t] raw dt cols f32
__device__ __align__(16) f16   g_xbc[(size_t)BL*CONVD];     // conv+silu; x cols overlaid by gated y
__device__ __align__(16) float g_a[BQ*NH*LQ];
__device__ __align__(16) float g_dt[BQ*NH*LQ];
__device__ __align__(16) float g_acum[BQ*NH*NCH*QC];
__device__ __align__(16) f16   g_G[(size_t)BQ*NCH*QC*QC];   // C@B^T per (b,c)
__device__ __align__(16) f16   g_yintra[(size_t)BQ*NH*NCH*HD*QC];  // [bh][c][p][t]
__device__ __align__(16) float g_sadd[(size_t)BQ*NH*NCH*HD*DS];
__device__ __align__(16) f16   g_sprev[(size_t)BQ*NH*NCH*HD*DS];
__device__ __align__(16) f16   g_yn[(size_t)BL*DI];
__device__ __align__(16) f16   g_Wout[(size_t)DM*DI];

__device__ __forceinline__ void gl_lds16(const void* g, void* l){
  __builtin_amdgcn_global_load_lds((const __attribute__((address_space(1))) unsigned int*)g,
                                   (__attribute__((address_space(3))) unsigned int*)l, 16, 0, 0);
}
__device__ __forceinline__ float silu_f(float v){ return v / (1.f + expf(-v)); }
__device__ __forceinline__ int swz(int row, int blk){ return blk ^ ((row ^ (row>>3)) & 15); }

// ---- weight casts ----
__global__ __launch_bounds__(256) void k_castWin(const float* __restrict__ W){
  int idx = blockIdx.x*256 + threadIdx.x;
  int row = idx / DM, col = idx % DM;
  float v = (row < NPROJ) ? W[(size_t)row*DM + col] : 0.f;
  g_Win[idx] = (f16)v;
}
__global__ __launch_bounds__(256) void k_castWout(const float* __restrict__ W){
  int idx = blockIdx.x*256 + threadIdx.x;
  g_Wout[idx] = (f16)W[idx];
}

// ---- LayerNorm -> f16 u ----
__global__ __launch_bounds__(256) void k_ln(const float* __restrict__ x,
                                            const float* __restrict__ lw,
                                            const float* __restrict__ lb){
  int r = blockIdx.x, tid = threadIdx.x;
  const float* xr = x + (size_t)r*DM;
  float v0 = xr[tid], v1 = xr[tid+256], v2 = xr[tid+512];
  float s = v0+v1+v2, q = v0*v0 + v1*v1 + v2*v2;
  __shared__ float red[8];
  #pragma unroll
  for (int o=32;o>0;o>>=1){ s += __shfl_down(s,o); q += __shfl_down(q,o); }
  if ((tid&63)==0){ red[tid>>6] = s; red[4+(tid>>6)] = q; }
  __syncthreads();
  float st = red[0]+red[1]+red[2]+red[3];
  float qt = red[4]+red[5]+red[6]+red[7];
  float mu = st * (1.f/DM);
  float var = qt * (1.f/DM) - mu*mu;
  float rs = rsqrtf(var + 1e-5f);
  f16* ur = g_u + (size_t)r*DM;
  ur[tid]     = (f16)((v0-mu)*rs*lw[tid]     + lb[tid]);
  ur[tid+256] = (f16)((v1-mu)*rs*lw[tid+256] + lb[tid+256]);
  ur[tid+512] = (f16)((v2-mu)*rs*lw[tid+512] + lb[tid+512]);
}

// ---- f16 MFMA GEMM, NT. MODE 0: -> g_zx f16 (+f32 dt cols). MODE 1: -> f32 out + resid ----
template<int N, int K, int MODE>
__device__ __forceinline__ void gemm_body(const f16* __restrict__ A, const f16* __restrict__ B,
                                          float* __restrict__ C, const float* __restrict__ resid){
  __shared__ __align__(16) f16 As[128*32];
  __shared__ __align__(16) f16 Bs[128*32];
  constexpr int NB = N/128;
  constexpr int NWG = (BL/128)*NB;      // grid size (M rows are always BL)
  constexpr int CPX = NWG/8;            // NWG % 8 == 0 for both GEMMs
  int bid = blockIdx.x;
  int swb = (bid & 7)*CPX + (bid >> 3); // bijective XCD swizzle (T1)
  int bm = swb / NB, bn = swb % NB;
  int m0 = bm*128, n0 = bn*128;
  int tid = threadIdx.x, lane = tid&63, w = tid>>6;
  int wr = w>>1, wc = w&1;
  int lm = lane&15, kg = lane>>4;
  f32x4 acc[4][4];
  #pragma unroll
  for (int i=0;i<4;i++)
    #pragma unroll
    for (int j=0;j<4;j++) acc[i][j] = (f32x4){0.f,0.f,0.f,0.f};
  for (int kt=0; kt<K/32; ++kt){
    int k0 = kt*32;
    #pragma unroll
    for (int it=0; it<2; ++it){
      int sg = tid + it*256;
      int row = sg>>2, ks = sg&3;
      gl_lds16(A + (size_t)(m0+row)*K + (k0+ks*8), (char*)As + sg*16);
      gl_lds16(B + (size_t)(n0+row)*K + (k0+ks*8), (char*)Bs + sg*16);
    }
    __syncthreads();
    hf8 fa[4], fb[4];
    #pragma unroll
    for (int i=0;i<4;i++) fa[i] = *(const hf8*)(As + (wr*64+i*16+lm)*32 + kg*8);
    #pragma unroll
    for (int j=0;j<4;j++) fb[j] = *(const hf8*)(Bs + (wc*64+j*16+lm)*32 + kg*8);
    #pragma unroll
    for (int i=0;i<4;i++)
      #pragma unroll
      for (int j=0;j<4;j++)
        acc[i][j] = __builtin_amdgcn_mfma_f32_16x16x32_f16(fa[i], fb[j], acc[i][j], 0,0,0);
    __syncthreads();
  }
  #pragma unroll
  for (int i=0;i<4;i++){
    #pragma unroll
    for (int j=0;j<4;j++){
      int colg = n0 + wc*64 + j*16 + lm;
      #pragma unroll
      for (int r=0;r<4;r++){
        int rowg = m0 + wr*64 + i*16 + kg*4 + r;
        float v = acc[i][j][r];
        if constexpr (MODE == 0){
          g_zx[(size_t)rowg*NPAD + colg] = (f16)v;
          if (colg >= DI+CONVD && colg < NPROJ)
            g_dtraw[(size_t)(colg-(DI+CONVD))*BL + rowg] = v;
        } else {
          C[(size_t)rowg*N + colg] = v + resid[(size_t)rowg*N + colg];
        }
      }
    }
  }
}
__global__ __launch_bounds__(256) void k_gemm1(){
  gemm_body<NPAD, DM, 0>(g_u, g_Win, nullptr, nullptr);
}
__global__ __launch_bounds__(256) void k_gemm2(float* __restrict__ out, const float* __restrict__ x){
  gemm_body<DM, DI, 1>(g_yn, g_Wout, out, x);
}

// ---- depthwise causal conv(4) + SiLU: one thread = one channel x 8 tokens ----
// cw load is one coalesced dwordx4/thread; x loads & y stores are 128B-contiguous
// per wave instruction (vs the old 64-line gather that serialized the TA).
__global__ __launch_bounds__(256) void k_conv(const float* __restrict__ cw, const float* __restrict__ cbv){
  int idx = blockIdx.x*256 + threadIdx.x;     // < (BL/8)*CONVD
  int c = idx % CONVD;                        // consecutive threads -> consecutive channels
  int g = idx / CONVD;                        // token octet
  int b = g / (LQ/8);
  int t0 = (g % (LQ/8)) * 8;
  const f16* base = &g_zx[((size_t)b*LQ + t0)*NPAD + DI + c];
  float xv[11];
  #pragma unroll
  for (int i=0;i<3;i++){
    int t = t0 - 3 + i;
    xv[i] = (t >= 0) ? (float)base[(ptrdiff_t)(i-3)*NPAD] : 0.f;
  }
  #pragma unroll
  for (int i=0;i<8;i++) xv[3+i] = (float)base[(size_t)i*NPAD];
  f32x4 wv = *(const f32x4*)&cw[c*4];
  float bias = cbv[c];
  f16* dst = &g_xbc[((size_t)b*LQ + t0)*CONVD + c];
  #pragma unroll
  for (int i=0;i<8;i++){
    float acc = bias + xv[i]*wv[0] + xv[i+1]*wv[1] + xv[i+2]*wv[2] + xv[i+3]*wv[3];
    dst[(size_t)i*CONVD] = (f16)silu_f(acc);
  }
}

// ---- dt softplus + log-decay a = dt*A ----
__global__ __launch_bounds__(256) void k_dadt(const float* __restrict__ dtb, const float* __restrict__ alog){
  int idx = blockIdx.x*256 + threadIdx.x;
  int t = idx % LQ, bh = idx / LQ;
  int h = bh % NH, bb = bh / NH;
  float raw = g_dtraw[(size_t)h*BL + bb*LQ + t] + dtb[h];
  float dt = (raw > 15.f) ? raw : log1pf(expf(raw));
  float A = -expf(alog[h]);
  g_dt[idx] = dt;
  g_a[idx] = dt * A;
}

// ---- G = C @ B^T per (b,c), head-independent ----
__global__ __launch_bounds__(256) void k_gpre(){
  __shared__ __align__(16) f16 Cs[QC*128];
  __shared__ __align__(16) f16 Bs[QC*128];
  int blk = blockIdx.x;            // bb*NCH + c
  int bb = blk / NCH, c = blk % NCH;
  size_t rb = (size_t)bb*LQ + (size_t)c*QC;
  int tid = threadIdx.x, lane = tid&63, w = tid>>6;
  #pragma unroll
  for (int it=0; it<8; ++it){
    int sg = tid + it*256;         // [0,2048)
    int t = sg>>4, nbd = sg&15;
    int nbs = swz(t, nbd);         // pre-swizzled source block
    gl_lds16(&g_xbc[(rb+t)*CONVD + DI    + nbs*8], (char*)Bs + sg*16);
    gl_lds16(&g_xbc[(rb+t)*CONVD + DI+DS + nbs*8], (char*)Cs + sg*16);
  }
  __syncthreads();
  int wr = w>>1, wc = w&1, lm = lane&15, kg = lane>>4;
  f32x4 acc[4][4];
  #pragma unroll
  for (int i=0;i<4;i++)
    #pragma unroll
    for (int j=0;j<4;j++) acc[i][j] = (f32x4){0.f,0.f,0.f,0.f};
  #pragma unroll
  for (int kk=0; kk<4; ++kk){
    hf8 fa[4], fb[4];
    #pragma unroll
    for (int i=0;i<4;i++){ int tc = wr*64+i*16+lm; fa[i] = *(const hf8*)&Cs[tc*128 + swz(tc, kk*4+kg)*8]; }
    #pragma unroll
    for (int j=0;j<4;j++){ int tb = wc*64+j*16+lm; fb[j] = *(const hf8*)&Bs[tb*128 + swz(tb, kk*4+kg)*8]; }
    #pragma unroll
    for (int i=0;i<4;i++)
      #pragma unroll
      for (int j=0;j<4;j++)
        acc[i][j] = __builtin_amdgcn_mfma_f32_16x16x32_f16(fa[i], fb[j], acc[i][j], 0,0,0);
  }
  f16* gdst = g_G + (size_t)blk*QC*128;
  #pragma unroll
  for (int i=0;i<4;i++)
    #pragma unroll
    for (int j=0;j<4;j++){
      int j_ = wc*64 + j*16 + lm;
      #pragma unroll
      for (int r=0;r<4;r++){
        int i_ = wr*64 + i*16 + kg*4 + r;
        gdst[(size_t)i_*128 + j_] = (f16)acc[i][j][r];
      }
    }
}

// ---- SSD phase A: per (b,h,c): Acum; M = G*decay; Y_intra = M@Xt^T; S_add = Xt@Btw^T ----
__global__ __launch_bounds__(512) void k_ssd_a(){
  __shared__ __align__(16) f16 Ms[QC*128];    // 32K, swizzled rows i
  __shared__ __align__(16) f16 Btw[DS*128];   // 32K, [n][t] swizzled
  __shared__ __align__(16) f16 Xt[HD*128];    // 16K, [p][t] swizzled
  __shared__ float Ac[QC];
  __shared__ float Dts[QC];
  __shared__ double dtot;
  int blk = blockIdx.x;
  int h = blk % NH; int bc = blk / NH;
  int c = bc % NCH; int bb = bc / NCH;
  int bh = bb*NH + h;
  int tid = threadIdx.x, lane = tid&63;
  size_t rb = (size_t)bb*LQ + (size_t)c*QC;
  size_t ab = (size_t)bh*LQ + (size_t)c*QC;

  double av = 0.0;
  if (tid < QC){
    av = (double)g_a[ab + tid];
    #pragma unroll
    for (int o=1;o<64;o<<=1){
      double nv = __shfl_up(av, o);
      if (lane >= o) av += nv;
    }
    if (tid == 63) dtot = av;
    Dts[tid] = g_dt[ab + tid];
  }
  __syncthreads();
  if (tid < QC){
    float ff = (float)(av + (tid >= 64 ? dtot : 0.0));
    Ac[tid] = ff;
    g_acum[((size_t)bh*NCH + c)*QC + tid] = ff;
  }
  __syncthreads();
  float Alast = Ac[QC-1];

  // stage Xt (threads 0..255) and Btw (threads 256..511)
  if (tid < 256){
    int pb = tid & 15, tb = tid >> 4;
    int p0 = pb*4, t0 = tb*8;
    f16 outv[4][8];
    #pragma unroll
    for (int r=0;r<8;r++){
      int t = t0 + r;
      hf4 xv = *(const hf4*)&g_xbc[(rb+t)*CONVD + h*HD + p0];
      float dtr = Dts[t];
      #pragma unroll
      for (int e=0;e<4;e++) outv[e][r] = (f16)((float)xv[e] * dtr);
    }
    #pragma unroll
    for (int e=0;e<4;e++){
      int p = p0 + e;
      *(hf8*)&Xt[p*128 + swz(p, tb)*8] = *(hf8*)outv[e];
    }
  } else {
    int tid2 = tid - 256;
    int nb = tid2 & 15, tb = tid2 >> 4;
    int n0 = nb*8, t0 = tb*8;
    f16 outv[8][8];
    #pragma unroll
    for (int r=0;r<8;r++){
      int t = t0 + r;
      hf8 bv = *(const hf8*)&g_xbc[(rb+t)*CONVD + DI + n0];
      float wr_ = expf(Alast - Ac[t]);
      #pragma unroll
      for (int e=0;e<8;e++) outv[e][r] = (f16)((float)bv[e] * wr_);
    }
    #pragma unroll
    for (int e=0;e<8;e++){
      int n = n0 + e;
      *(hf8*)&Btw[n*128 + swz(n, tb)*8] = *(hf8*)outv[e];
    }
  }
  // stage Ms = G * decay mask (all 512 threads: row i = tid>>2, 32 j's)
  {
    int i_ = tid >> 2;
    int j0 = (tid & 3) * 32;
    float ai = Ac[i_];
    const f16* gsrc = &g_G[(size_t)(bb*NCH + c)*QC*128 + (size_t)i_*128 + j0];
    #pragma unroll
    for (int u=0; u<4; ++u){
      hf8 gv = *(const hf8*)(gsrc + u*8);
      f16 mv[8];
      #pragma unroll
      for (int e=0;e<8;e++){
        int j = j0 + u*8 + e;
        float m = (j <= i_) ? (float)gv[e] * expf(ai - Ac[j]) : 0.f;
        mv[e] = (f16)m;
      }
      *(hf8*)&Ms[i_*128 + swz(i_, j0/8 + u)*8] = *(hf8*)mv;
    }
  }
  __syncthreads();

  int w = tid>>6, lm = lane&15, kg = lane>>4;

  // Y_intra = Ms @ Xt^T (128 x 64): waves 4x2
  {
    int wr = w>>1, wc = w&1;
    f32x4 acc2[2][2];
    #pragma unroll
    for (int i=0;i<2;i++){ acc2[i][0]=(f32x4){0,0,0,0}; acc2[i][1]=(f32x4){0,0,0,0}; }
    #pragma unroll
    for (int kk=0; kk<4; ++kk){
      hf8 fa[2], fb[2];
      #pragma unroll
      for (int ii=0;ii<2;ii++){ int i_ = wr*32+ii*16+lm; fa[ii] = *(const hf8*)&Ms[i_*128 + swz(i_, kk*4+kg)*8]; }
      #pragma unroll
      for (int jj=0;jj<2;jj++){ int p_ = wc*32+jj*16+lm; fb[jj] = *(const hf8*)&Xt[p_*128 + swz(p_, kk*4+kg)*8]; }
      #pragma unroll
      for (int ii=0;ii<2;ii++)
        #pragma unroll
        for (int jj=0;jj<2;jj++)
          acc2[ii][jj] = __builtin_amdgcn_mfma_f32_16x16x32_f16(fa[ii], fb[jj], acc2[ii][jj], 0,0,0);
    }
    size_t yb = ((size_t)bh*NCH + c)*(HD*QC);
    #pragma unroll
    for (int ii=0;ii<2;ii++)
      #pragma unroll
      for (int jj=0;jj<2;jj++){
        int p_ = wc*32 + jj*16 + lm;
        int i0 = wr*32 + ii*16 + kg*4;
        f16 vv[4];
        #pragma unroll
        for (int r=0;r<4;r++) vv[r] = (f16)acc2[ii][jj][r];
        *(hf4*)&g_yintra[yb + (size_t)p_*QC + i0] = *(hf4*)vv;
      }
  }
  // S_add = Xt @ Btw^T (64 x 128): waves 2x4
  {
    int wr = w>>2, wc = w&3;
    f32x4 acc3[2][2];
    #pragma unroll
    for (int i=0;i<2;i++){ acc3[i][0]=(f32x4){0,0,0,0}; acc3[i][1]=(f32x4){0,0,0,0}; }
    #pragma unroll
    for (int kk=0; kk<4; ++kk){
      hf8 fa[2], fb[2];
      #pragma unroll
      for (int ii=0;ii<2;ii++){ int p_ = wr*32+ii*16+lm; fa[ii] = *(const hf8*)&Xt[p_*128 + swz(p_, kk*4+kg)*8]; }
      #pragma unroll
      for (int jj=0;jj<2;jj++){ int n_ = wc*32+jj*16+lm; fb[jj] = *(const hf8*)&Btw[n_*128 + swz(n_, kk*4+kg)*8]; }
      #pragma unroll
      for (int ii=0;ii<2;ii++)
        #pragma unroll
        for (int jj=0;jj<2;jj++)
          acc3[ii][jj] = __builtin_amdgcn_mfma_f32_16x16x32_f16(fa[ii], fb[jj], acc3[ii][jj], 0,0,0);
    }
    size_t sb = ((size_t)bh*NCH + c)*HD*DS;
    #pragma unroll
    for (int ii=0;ii<2;ii++)
      #pragma unroll
      for (int jj=0;jj<2;jj++){
        int n_ = wc*32 + jj*16 + lm;
        #pragma unroll
        for (int r=0;r<4;r++){
          int p_ = wr*32 + ii*16 + kg*4 + r;
          g_sadd[sb + (size_t)p_*DS + n_] = acc3[ii][jj][r];
        }
      }
  }
}

// ---- SSD phase B: inter-chunk state recurrence ----
__global__ __launch_bounds__(256) void k_ssd_b(){
  int bh = blockIdx.x >> 5;
  int pn = (blockIdx.x & 31)*256 + threadIdx.x;
  float s = 0.f;
  size_t base = (size_t)bh*NCH;
  for (int c=0;c<NCH;c++){
    size_t o = (base + c)*(HD*DS) + pn;
    g_sprev[o] = (f16)s;
    float T = expf(g_acum[(base + c)*QC + (QC-1)]);
    s = s*T + g_sadd[o];
  }
}

// ---- SSD phase C: Y = Y_intra + (e*C)@s_prev^T + D*x; gate; write ygate ----
__global__ __launch_bounds__(256) void k_ssd_c(const float* __restrict__ Dp){
  __shared__ __align__(16) f16 Csc[QC*SPAD2];
  __shared__ __align__(16) f16 Sp[HD*SPAD2];
  __shared__ float Ex[QC];
  int blk = blockIdx.x;
  int h = blk % NH; int bc = blk / NH;
  int c = bc % NCH; int bb = bc / NCH;
  int bh = bb*NH + h;
  int tid = threadIdx.x, lane = tid&63, w = tid>>6;
  int wr = w>>1, wc = w&1, lm = lane&15, kg = lane>>4;
  size_t rb = (size_t)bb*LQ + (size_t)c*QC;
  if (tid < QC) Ex[tid] = expf(g_acum[((size_t)bh*NCH + c)*QC + tid]);
  __syncthreads();
  #pragma unroll
  for (int it=0; it<8; ++it){
    int sg = tid + it*256;            // [0,2048)
    int row = sg>>4, bk = sg&15;
    hf8 cv = *(const hf8*)&g_xbc[(rb+row)*CONVD + DI+DS + bk*8];
    float e = Ex[row];
    f16 tc[8];
    #pragma unroll
    for (int k2=0;k2<8;k2++) tc[k2] = (f16)((float)cv[k2]*e);
    *(hf8*)&Csc[row*SPAD2 + bk*8] = *(hf8*)tc;
  }
  const f16* sp = &g_sprev[((size_t)bh*NCH + c)*HD*DS];
  #pragma unroll
  for (int it=0; it<4; ++it){
    int sg = tid + it*256;            // [0,1024)
    int row = sg>>4, bk = sg&15;
    *(hf8*)&Sp[row*SPAD2 + bk*8] = *(const hf8*)(sp + row*DS + bk*8);
  }
  __syncthreads();
  f32x4 acc[4][2];
  #pragma unroll
  for (int i=0;i<4;i++){ acc[i][0]=(f32x4){0,0,0,0}; acc[i][1]=(f32x4){0,0,0,0}; }
  #pragma unroll
  for (int kk=0; kk<4; ++kk){
    hf8 fa[4], fb[2];
    #pragma unroll
    for (int i=0;i<4;i++) fa[i] = *(const hf8*)&Csc[(wr*64+i*16+lm)*SPAD2 + kk*32 + kg*8];
    #pragma unroll
    for (int j=0;j<2;j++) fb[j] = *(const hf8*)&Sp[(wc*32+j*16+lm)*SPAD2 + kk*32 + kg*8];
    #pragma unroll
    for (int i=0;i<4;i++)
      #pragma unroll
      for (int j=0;j<2;j++)
        acc[i][j] = __builtin_amdgcn_mfma_f32_16x16x32_f16(fa[i], fb[j], acc[i][j], 0,0,0);
  }
  float Dh = Dp[h];
  size_t yb = ((size_t)bh*NCH + c)*(HD*QC);
  #pragma unroll
  for (int it=0;it<4;it++)
    #pragma unroll
    for (int jt=0;jt<2;jt++){
      int p_ = wc*32 + jt*16 + lm;
      int i0 = wr*64 + it*16 + kg*4;
      hf4 yi = *(const hf4*)&g_yintra[yb + (size_t)p_*QC + i0];
      #pragma unroll
      for (int r=0;r<4;r++){
        int i_ = i0 + r;
        size_t t = rb + i_;
        float xv = (float)g_xbc[t*CONVD + h*HD + p_];
        float zv = (float)g_zx [t*NPAD  + h*HD + p_];
        float y = acc[it][jt][r] + (float)yi[r] + Dh*xv;
        g_xbc[t*CONVD + h*HD + p_] = (f16)(y * silu_f(zv));
      }
    }
}

// ---- RMSNorm of gated y -> f16 ----
__global__ __launch_bounds__(256) void k_rms(const float* __restrict__ nw){
  int r = blockIdx.x, tid = threadIdx.x;
  const f16* yr = g_xbc + (size_t)r*CONVD;
  float v[6]; float q = 0.f;
  #pragma unroll
  for (int i=0;i<6;i++){ v[i] = (float)yr[tid + i*256]; q += v[i]*v[i]; }
  __shared__ float red[4];
  #pragma unroll
  for (int o=32;o>0;o>>=1) q += __shfl_down(q,o);
  if ((tid&63)==0) red[tid>>6] = q;
  __syncthreads();
  float qt = red[0]+red[1]+red[2]+red[3];
  float sc = rsqrtf(qt*(1.f/DI) + 1e-5f);
  f16* dst = g_yn + (size_t)r*DI;
  #pragma unroll
  for (int i=0;i<6;i++) dst[tid + i*256] = (f16)(v[i]*sc*nw[tid + i*256]);
}

extern "C" void kernel_launch(void* const* d_in, const int* in_sizes, int n_in,
                              void* d_out, int out_size, void* d_ws, size_t ws_size,
                              hipStream_t stream){
  const float* x    = (const float*)d_in[0];
  const float* Win  = (const float*)d_in[1];
  const float* cw   = (const float*)d_in[2];
  const float* cbv  = (const float*)d_in[3];
  const float* dtb  = (const float*)d_in[4];
  const float* alog = (const float*)d_in[5];
  const float* Dv   = (const float*)d_in[6];
  const float* nw   = (const float*)d_in[7];
  const float* Wout = (const float*)d_in[8];
  const float* lnw  = (const float*)d_in[9];
  const float* lnb  = (const float*)d_in[10];
  float* out = (float*)d_out;

  k_castWin <<<(NPAD*DM)/256, 256, 0, stream>>>(Win);
  k_castWout<<<(DM*DI)/256,   256, 0, stream>>>(Wout);
  k_ln      <<<BL,            256, 0, stream>>>(x, lnw, lnb);
  k_gemm1   <<<(BL/128)*(NPAD/128), 256, 0, stream>>>();
  k_conv    <<<((BL/8)*CONVD)/256, 256, 0, stream>>>(cw, cbv);
  k_dadt    <<<(BQ*NH*LQ)/256, 256, 0, stream>>>(dtb, alog);
  k_gpre    <<<BQ*NCH,        256, 0, stream>>>();
  k_ssd_a   <<<BQ*NCH*NH,     512, 0, stream>>>();
  k_ssd_b   <<<BQ*NH*32,      256, 0, stream>>>();
  k_ssd_c   <<<BQ*NCH*NH,     256, 0, stream>>>(Dv);
  k_rms     <<<BL,            256, 0, stream>>>(nw);
  k_gemm2   <<<(BL/128)*(DM/128), 256, 0, stream>>>(out, x);
}

// Round 7
// 707.965 us; speedup vs baseline: 2.7661x; 1.0334x over previous
//
#include <hip/hip_runtime.h>
#include <hip/hip_bf16.h>
#include <math.h>

#define BQ 8
#define LQ 2048
#define DM 768
#define DI 1536
#define DS 128
#define NH 24
#define HD 64
#define CONVD 1792          // DI + 2*DS
#define NPROJ 3352          // 2*DI + 2*DS + NH
#define NPAD 3584           // NPROJ padded to 256 (for 256x256 GEMM tiles)
#define BL (BQ*LQ)          // 16384 tokens
#define QC 128              // SSD chunk length
#define NCH (LQ/QC)         // 16 chunks per sequence
#define SPAD2 136           // padded LDS row stride for ssd_c (f16)

using f32x4 = __attribute__((ext_vector_type(4))) float;
typedef _Float16 f16;
using hf8 = __attribute__((ext_vector_type(8))) _Float16;
using hf4 = __attribute__((ext_vector_type(4))) _Float16;

// ---- static scratch ----
__device__ __align__(16) f16   g_u[(size_t)BL*DM];
__device__ __align__(16) f16   g_Win[(size_t)NPAD*DM];
__device__ __align__(16) f16   g_zx[(size_t)BL*NPAD];       // zxbcdt f16
__device__ __align__(16) float g_dtraw[(size_t)NH*BL];      // [h][b*t] raw dt cols f32
__device__ __align__(16) f16   g_xbc[(size_t)BL*CONVD];     // conv+silu; x cols overlaid by gated y
__device__ __align__(16) float g_a[BQ*NH*LQ];
__device__ __align__(16) float g_dt[BQ*NH*LQ];
__device__ __align__(16) float g_acum[BQ*NH*NCH*QC];
__device__ __align__(16) f16   g_G[(size_t)BQ*NCH*QC*QC];   // C@B^T per (b,c)
__device__ __align__(16) f16   g_yintra[(size_t)BQ*NH*NCH*HD*QC];  // [bh][c][p][t]
__device__ __align__(16) float g_sadd[(size_t)BQ*NH*NCH*HD*DS];
__device__ __align__(16) f16   g_sprev[(size_t)BQ*NH*NCH*HD*DS];
__device__ __align__(16) f16   g_yn[(size_t)BL*DI];
__device__ __align__(16) f16   g_Wout[(size_t)DM*DI];

__device__ __forceinline__ void gl_lds16(const void* g, void* l){
  __builtin_amdgcn_global_load_lds((const __attribute__((address_space(1))) unsigned int*)g,
                                   (__attribute__((address_space(3))) unsigned int*)l, 16, 0, 0);
}
__device__ __forceinline__ float silu_f(float v){ return v / (1.f + expf(-v)); }
__device__ __forceinline__ int swz(int row, int blk){ return blk ^ ((row ^ (row>>3)) & 15); }

// ---- weight casts ----
__global__ __launch_bounds__(256) void k_castWin(const float* __restrict__ W){
  int idx = blockIdx.x*256 + threadIdx.x;
  int row = idx / DM, col = idx % DM;
  float v = (row < NPROJ) ? W[(size_t)row*DM + col] : 0.f;
  g_Win[idx] = (f16)v;
}
__global__ __launch_bounds__(256) void k_castWout(const float* __restrict__ W){
  int idx = blockIdx.x*256 + threadIdx.x;
  g_Wout[idx] = (f16)W[idx];
}

// ---- LayerNorm -> f16 u ----
__global__ __launch_bounds__(256) void k_ln(const float* __restrict__ x,
                                            const float* __restrict__ lw,
                                            const float* __restrict__ lb){
  int r = blockIdx.x, tid = threadIdx.x;
  const float* xr = x + (size_t)r*DM;
  float v0 = xr[tid], v1 = xr[tid+256], v2 = xr[tid+512];
  float s = v0+v1+v2, q = v0*v0 + v1*v1 + v2*v2;
  __shared__ float red[8];
  #pragma unroll
  for (int o=32;o>0;o>>=1){ s += __shfl_down(s,o); q += __shfl_down(q,o); }
  if ((tid&63)==0){ red[tid>>6] = s; red[4+(tid>>6)] = q; }
  __syncthreads();
  float st = red[0]+red[1]+red[2]+red[3];
  float qt = red[4]+red[5]+red[6]+red[7];
  float mu = st * (1.f/DM);
  float var = qt * (1.f/DM) - mu*mu;
  float rs = rsqrtf(var + 1e-5f);
  f16* ur = g_u + (size_t)r*DM;
  ur[tid]     = (f16)((v0-mu)*rs*lw[tid]     + lb[tid]);
  ur[tid+256] = (f16)((v1-mu)*rs*lw[tid+256] + lb[tid+256]);
  ur[tid+512] = (f16)((v2-mu)*rs*lw[tid+512] + lb[tid+512]);
}

// ---- 256x256 f16 MFMA GEMM, NT, double-buffered LDS, counted-vmcnt pipeline ----
// MODE 0: -> g_zx f16 (+f32 dt cols). MODE 1: -> f32 out + resid.
// LDS layout: [row][64] f16 per tile, 16B blocks XOR-swizzled with (row&7)
// (staged linearly via pre-swizzled global source; read with same XOR -> 2-way conflicts only).
template<int N, int K, int MODE>
__device__ __forceinline__ void gemm_body(const f16* __restrict__ A, const f16* __restrict__ B,
                                          float* __restrict__ C, const float* __restrict__ resid){
  __shared__ __align__(16) f16 As[2][256*64];
  __shared__ __align__(16) f16 Bs[2][256*64];
  constexpr int NB = N/256;
  constexpr int NWG = (BL/256)*NB;
  constexpr int CPX = NWG/8;            // NWG % 8 == 0 for both GEMMs
  constexpr int NT = K/64;
  int bid = blockIdx.x;
  int swb = (bid & 7)*CPX + (bid >> 3); // bijective XCD swizzle (T1)
  int bm = swb / NB, bn = swb % NB;
  int m0 = bm*256, n0 = bn*256;
  int tid = threadIdx.x, lane = tid&63, w = tid>>6;
  int wr = w>>2, wc = w&3;              // 2 x 4 wave grid; per-wave out 128x64
  int lm = lane&15, kg = lane>>4;

  auto stage = [&](int buf, int kt){
    #pragma unroll
    for (int i=0;i<4;i++){
      int seg = i*512 + tid;            // [0,2048): 256 rows x 8 16B-blocks
      int row = seg>>3, blk = seg&7;
      int bsrc = blk ^ (row&7);
      gl_lds16(A + (size_t)(m0+row)*K + kt*64 + bsrc*8, (char*)&As[buf][0] + seg*16);
    }
    #pragma unroll
    for (int i=0;i<4;i++){
      int seg = i*512 + tid;
      int row = seg>>3, blk = seg&7;
      int bsrc = blk ^ (row&7);
      gl_lds16(B + (size_t)(n0+row)*K + kt*64 + bsrc*8, (char*)&Bs[buf][0] + seg*16);
    }
  };

  f32x4 acc[8][4];
  #pragma unroll
  for (int i=0;i<8;i++)
    #pragma unroll
    for (int j=0;j<4;j++) acc[i][j] = (f32x4){0.f,0.f,0.f,0.f};

  stage(0, 0);
  if (NT > 1) stage(1, 1);
  for (int kt=0; kt<NT; ++kt){
    int cb = kt & 1;
    // own loads for tile kt are older than the (at most) 8 for tile kt+1
    if (kt+1 < NT) asm volatile("s_waitcnt vmcnt(8)" ::: "memory");
    else           asm volatile("s_waitcnt vmcnt(0)" ::: "memory");
    asm volatile("s_barrier" ::: "memory");   // raw barrier: no auto vmcnt(0) drain
    #pragma unroll
    for (int kk=0;kk<2;kk++){
      hf8 fa[8], fb[4];
      #pragma unroll
      for (int i=0;i<8;i++){
        int r = wr*128 + i*16 + lm;
        int blk = (kk*4+kg) ^ (r&7);
        fa[i] = *(const hf8*)&As[cb][r*64 + blk*8];
      }
      #pragma unroll
      for (int j=0;j<4;j++){
        int r = wc*64 + j*16 + lm;
        int blk = (kk*4+kg) ^ (r&7);
        fb[j] = *(const hf8*)&Bs[cb][r*64 + blk*8];
      }
      #pragma unroll
      for (int i=0;i<8;i++)
        #pragma unroll
        for (int j=0;j<4;j++)
          acc[i][j] = __builtin_amdgcn_mfma_f32_16x16x32_f16(fa[i], fb[j], acc[i][j], 0,0,0);
    }
    asm volatile("s_barrier" ::: "memory");   // all waves done reading buf cb
    if (kt+2 < NT) stage(cb, kt+2);           // refill just-freed buffer
  }

  #pragma unroll
  for (int i=0;i<8;i++){
    #pragma unroll
    for (int j=0;j<4;j++){
      int colg = n0 + wc*64 + j*16 + lm;
      #pragma unroll
      for (int r=0;r<4;r++){
        int rowg = m0 + wr*128 + i*16 + kg*4 + r;
        float v = acc[i][j][r];
        if constexpr (MODE == 0){
          g_zx[(size_t)rowg*NPAD + colg] = (f16)v;
          if (colg >= DI+CONVD && colg < NPROJ)
            g_dtraw[(size_t)(colg-(DI+CONVD))*BL + rowg] = v;
        } else {
          C[(size_t)rowg*N + colg] = v + resid[(size_t)rowg*N + colg];
        }
      }
    }
  }
}
__global__ __launch_bounds__(512,2) void k_gemm1(){
  gemm_body<NPAD, DM, 0>(g_u, g_Win, nullptr, nullptr);
}
__global__ __launch_bounds__(512,2) void k_gemm2(float* __restrict__ out, const float* __restrict__ x){
  gemm_body<DM, DI, 1>(g_yn, g_Wout, out, x);
}

// ---- depthwise causal conv(4) + SiLU: one thread = one channel x 8 tokens ----
__global__ __launch_bounds__(256) void k_conv(const float* __restrict__ cw, const float* __restrict__ cbv){
  int idx = blockIdx.x*256 + threadIdx.x;     // < (BL/8)*CONVD
  int c = idx % CONVD;                        // consecutive threads -> consecutive channels
  int g = idx / CONVD;                        // token octet
  int b = g / (LQ/8);
  int t0 = (g % (LQ/8)) * 8;
  const f16* base = &g_zx[((size_t)b*LQ + t0)*NPAD + DI + c];
  float xv[11];
  #pragma unroll
  for (int i=0;i<3;i++){
    int t = t0 - 3 + i;
    xv[i] = (t >= 0) ? (float)base[(ptrdiff_t)(i-3)*NPAD] : 0.f;
  }
  #pragma unroll
  for (int i=0;i<8;i++) xv[3+i] = (float)base[(size_t)i*NPAD];
  f32x4 wv = *(const f32x4*)&cw[c*4];
  float bias = cbv[c];
  f16* dst = &g_xbc[((size_t)b*LQ + t0)*CONVD + c];
  #pragma unroll
  for (int i=0;i<8;i++){
    float acc = bias + xv[i]*wv[0] + xv[i+1]*wv[1] + xv[i+2]*wv[2] + xv[i+3]*wv[3];
    dst[(size_t)i*CONVD] = (f16)silu_f(acc);
  }
}

// ---- dt softplus + log-decay a = dt*A ----
__global__ __launch_bounds__(256) void k_dadt(const float* __restrict__ dtb, const float* __restrict__ alog){
  int idx = blockIdx.x*256 + threadIdx.x;
  int t = idx % LQ, bh = idx / LQ;
  int h = bh % NH, bb = bh / NH;
  float raw = g_dtraw[(size_t)h*BL + bb*LQ + t] + dtb[h];
  float dt = (raw > 15.f) ? raw : log1pf(expf(raw));
  float A = -expf(alog[h]);
  g_dt[idx] = dt;
  g_a[idx] = dt * A;
}

// ---- G = C @ B^T per (b,c), head-independent ----
__global__ __launch_bounds__(256) void k_gpre(){
  __shared__ __align__(16) f16 Cs[QC*128];
  __shared__ __align__(16) f16 Bs[QC*128];
  int blk = blockIdx.x;            // bb*NCH + c
  int bb = blk / NCH, c = blk % NCH;
  size_t rb = (size_t)bb*LQ + (size_t)c*QC;
  int tid = threadIdx.x, lane = tid&63, w = tid>>6;
  #pragma unroll
  for (int it=0; it<8; ++it){
    int sg = tid + it*256;         // [0,2048)
    int t = sg>>4, nbd = sg&15;
    int nbs = swz(t, nbd);         // pre-swizzled source block
    gl_lds16(&g_xbc[(rb+t)*CONVD + DI    + nbs*8], (char*)Bs + sg*16);
    gl_lds16(&g_xbc[(rb+t)*CONVD + DI+DS + nbs*8], (char*)Cs + sg*16);
  }
  __syncthreads();
  int wr = w>>1, wc = w&1, lm = lane&15, kg = lane>>4;
  f32x4 acc[4][4];
  #pragma unroll
  for (int i=0;i<4;i++)
    #pragma unroll
    for (int j=0;j<4;j++) acc[i][j] = (f32x4){0.f,0.f,0.f,0.f};
  #pragma unroll
  for (int kk=0; kk<4; ++kk){
    hf8 fa[4], fb[4];
    #pragma unroll
    for (int i=0;i<4;i++){ int tc = wr*64+i*16+lm; fa[i] = *(const hf8*)&Cs[tc*128 + swz(tc, kk*4+kg)*8]; }
    #pragma unroll
    for (int j=0;j<4;j++){ int tb = wc*64+j*16+lm; fb[j] = *(const hf8*)&Bs[tb*128 + swz(tb, kk*4+kg)*8]; }
    #pragma unroll
    for (int i=0;i<4;i++)
      #pragma unroll
      for (int j=0;j<4;j++)
        acc[i][j] = __builtin_amdgcn_mfma_f32_16x16x32_f16(fa[i], fb[j], acc[i][j], 0,0,0);
  }
  f16* gdst = g_G + (size_t)blk*QC*128;
  #pragma unroll
  for (int i=0;i<4;i++)
    #pragma unroll
    for (int j=0;j<4;j++){
      int j_ = wc*64 + j*16 + lm;
      #pragma unroll
      for (int r=0;r<4;r++){
        int i_ = wr*64 + i*16 + kg*4 + r;
        gdst[(size_t)i_*128 + j_] = (f16)acc[i][j][r];
      }
    }
}

// ---- SSD phase A: per (b,h,c): Acum; M = G*decay; Y_intra = M@Xt^T; S_add = Xt@Btw^T ----
__global__ __launch_bounds__(512) void k_ssd_a(){
  __shared__ __align__(16) f16 Ms[QC*128];    // 32K, swizzled rows i
  __shared__ __align__(16) f16 Btw[DS*128];   // 32K, [n][t] swizzled
  __shared__ __align__(16) f16 Xt[HD*128];    // 16K, [p][t] swizzled
  __shared__ float Ac[QC];
  __shared__ float Dts[QC];
  __shared__ double dtot;
  int blk = blockIdx.x;
  int h = blk % NH; int bc = blk / NH;
  int c = bc % NCH; int bb = bc / NCH;
  int bh = bb*NH + h;
  int tid = threadIdx.x, lane = tid&63;
  size_t rb = (size_t)bb*LQ + (size_t)c*QC;
  size_t ab = (size_t)bh*LQ + (size_t)c*QC;

  double av = 0.0;
  if (tid < QC){
    av = (double)g_a[ab + tid];
    #pragma unroll
    for (int o=1;o<64;o<<=1){
      double nv = __shfl_up(av, o);
      if (lane >= o) av += nv;
    }
    if (tid == 63) dtot = av;
    Dts[tid] = g_dt[ab + tid];
  }
  __syncthreads();
  if (tid < QC){
    float ff = (float)(av + (tid >= 64 ? dtot : 0.0));
    Ac[tid] = ff;
    g_acum[((size_t)bh*NCH + c)*QC + tid] = ff;
  }
  __syncthreads();
  float Alast = Ac[QC-1];

  // stage Xt (threads 0..255) and Btw (threads 256..511)
  if (tid < 256){
    int pb = tid & 15, tb = tid >> 4;
    int p0 = pb*4, t0 = tb*8;
    f16 outv[4][8];
    #pragma unroll
    for (int r=0;r<8;r++){
      int t = t0 + r;
      hf4 xv = *(const hf4*)&g_xbc[(rb+t)*CONVD + h*HD + p0];
      float dtr = Dts[t];
      #pragma unroll
      for (int e=0;e<4;e++) outv[e][r] = (f16)((float)xv[e] * dtr);
    }
    #pragma unroll
    for (int e=0;e<4;e++){
      int p = p0 + e;
      *(hf8*)&Xt[p*128 + swz(p, tb)*8] = *(hf8*)outv[e];
    }
  } else {
    int tid2 = tid - 256;
    int nb = tid2 & 15, tb = tid2 >> 4;
    int n0 = nb*8, t0 = tb*8;
    f16 outv[8][8];
    #pragma unroll
    for (int r=0;r<8;r++){
      int t = t0 + r;
      hf8 bv = *(const hf8*)&g_xbc[(rb+t)*CONVD + DI + n0];
      float wr_ = expf(Alast - Ac[t]);
      #pragma unroll
      for (int e=0;e<8;e++) outv[e][r] = (f16)((float)bv[e] * wr_);
    }
    #pragma unroll
    for (int e=0;e<8;e++){
      int n = n0 + e;
      *(hf8*)&Btw[n*128 + swz(n, tb)*8] = *(hf8*)outv[e];
    }
  }
  // stage Ms = G * decay mask (all 512 threads: row i = tid>>2, 32 j's)
  {
    int i_ = tid >> 2;
    int j0 = (tid & 3) * 32;
    float ai = Ac[i_];
    const f16* gsrc = &g_G[(size_t)(bb*NCH + c)*QC*128 + (size_t)i_*128 + j0];
    #pragma unroll
    for (int u=0; u<4; ++u){
      hf8 gv = *(const hf8*)(gsrc + u*8);
      f16 mv[8];
      #pragma unroll
      for (int e=0;e<8;e++){
        int j = j0 + u*8 + e;
        float m = (j <= i_) ? (float)gv[e] * expf(ai - Ac[j]) : 0.f;
        mv[e] = (f16)m;
      }
      *(hf8*)&Ms[i_*128 + swz(i_, j0/8 + u)*8] = *(hf8*)mv;
    }
  }
  __syncthreads();

  int w = tid>>6, lm = lane&15, kg = lane>>4;

  // Y_intra = Ms @ Xt^T (128 x 64): waves 4x2
  {
    int wr = w>>1, wc = w&1;
    f32x4 acc2[2][2];
    #pragma unroll
    for (int i=0;i<2;i++){ acc2[i][0]=(f32x4){0,0,0,0}; acc2[i][1]=(f32x4){0,0,0,0}; }
    #pragma unroll
    for (int kk=0; kk<4; ++kk){
      hf8 fa[2], fb[2];
      #pragma unroll
      for (int ii=0;ii<2;ii++){ int i_ = wr*32+ii*16+lm; fa[ii] = *(const hf8*)&Ms[i_*128 + swz(i_, kk*4+kg)*8]; }
      #pragma unroll
      for (int jj=0;jj<2;jj++){ int p_ = wc*32+jj*16+lm; fb[jj] = *(const hf8*)&Xt[p_*128 + swz(p_, kk*4+kg)*8]; }
      #pragma unroll
      for (int ii=0;ii<2;ii++)
        #pragma unroll
        for (int jj=0;jj<2;jj++)
          acc2[ii][jj] = __builtin_amdgcn_mfma_f32_16x16x32_f16(fa[ii], fb[jj], acc2[ii][jj], 0,0,0);
    }
    size_t yb = ((size_t)bh*NCH + c)*(HD*QC);
    #pragma unroll
    for (int ii=0;ii<2;ii++)
      #pragma unroll
      for (int jj=0;jj<2;jj++){
        int p_ = wc*32 + jj*16 + lm;
        int i0 = wr*32 + ii*16 + kg*4;
        f16 vv[4];
        #pragma unroll
        for (int r=0;r<4;r++) vv[r] = (f16)acc2[ii][jj][r];
        *(hf4*)&g_yintra[yb + (size_t)p_*QC + i0] = *(hf4*)vv;
      }
  }
  // S_add = Xt @ Btw^T (64 x 128): waves 2x4
  {
    int wr = w>>2, wc = w&3;
    f32x4 acc3[2][2];
    #pragma unroll
    for (int i=0;i<2;i++){ acc3[i][0]=(f32x4){0,0,0,0}; acc3[i][1]=(f32x4){0,0,0,0}; }
    #pragma unroll
    for (int kk=0; kk<4; ++kk){
      hf8 fa[2], fb[2];
      #pragma unroll
      for (int ii=0;ii<2;ii++){ int p_ = wr*32+ii*16+lm; fa[ii] = *(const hf8*)&Xt[p_*128 + swz(p_, kk*4+kg)*8]; }
      #pragma unroll
      for (int jj=0;jj<2;jj++){ int n_ = wc*32+jj*16+lm; fb[jj] = *(const hf8*)&Btw[n_*128 + swz(n_, kk*4+kg)*8]; }
      #pragma unroll
      for (int ii=0;ii<2;ii++)
        #pragma unroll
        for (int jj=0;jj<2;jj++)
          acc3[ii][jj] = __builtin_amdgcn_mfma_f32_16x16x32_f16(fa[ii], fb[jj], acc3[ii][jj], 0,0,0);
    }
    size_t sb = ((size_t)bh*NCH + c)*HD*DS;
    #pragma unroll
    for (int ii=0;ii<2;ii++)
      #pragma unroll
      for (int jj=0;jj<2;jj++){
        int n_ = wc*32 + jj*16 + lm;
        #pragma unroll
        for (int r=0;r<4;r++){
          int p_ = wr*32 + ii*16 + kg*4 + r;
          g_sadd[sb + (size_t)p_*DS + n_] = acc3[ii][jj][r];
        }
      }
  }
}

// ---- SSD phase B: inter-chunk state recurrence ----
__global__ __launch_bounds__(256) void k_ssd_b(){
  int bh = blockIdx.x >> 5;
  int pn = (blockIdx.x & 31)*256 + threadIdx.x;
  float s = 0.f;
  size_t base = (size_t)bh*NCH;
  for (int c=0;c<NCH;c++){
    size_t o = (base + c)*(HD*DS) + pn;
    g_sprev[o] = (f16)s;
    float T = expf(g_acum[(base + c)*QC + (QC-1)]);
    s = s*T + g_sadd[o];
  }
}

// ---- SSD phase C: Y = Y_intra + (e*C)@s_prev^T + D*x; gate; write ygate ----
__global__ __launch_bounds__(256) void k_ssd_c(const float* __restrict__ Dp){
  __shared__ __align__(16) f16 Csc[QC*SPAD2];
  __shared__ __align__(16) f16 Sp[HD*SPAD2];
  __shared__ float Ex[QC];
  int blk = blockIdx.x;
  int h = blk % NH; int bc = blk / NH;
  int c = bc % NCH; int bb = bc / NCH;
  int bh = bb*NH + h;
  int tid = threadIdx.x, lane = tid&63, w = tid>>6;
  int wr = w>>1, wc = w&1, lm = lane&15, kg = lane>>4;
  size_t rb = (size_t)bb*LQ + (size_t)c*QC;
  if (tid < QC) Ex[tid] = expf(g_acum[((size_t)bh*NCH + c)*QC + tid]);
  __syncthreads();
  #pragma unroll
  for (int it=0; it<8; ++it){
    int sg = tid + it*256;            // [0,2048)
    int row = sg>>4, bk = sg&15;
    hf8 cv = *(const hf8*)&g_xbc[(rb+row)*CONVD + DI+DS + bk*8];
    float e = Ex[row];
    f16 tc[8];
    #pragma unroll
    for (int k2=0;k2<8;k2++) tc[k2] = (f16)((float)cv[k2]*e);
    *(hf8*)&Csc[row*SPAD2 + bk*8] = *(hf8*)tc;
  }
  const f16* sp = &g_sprev[((size_t)bh*NCH + c)*HD*DS];
  #pragma unroll
  for (int it=0; it<4; ++it){
    int sg = tid + it*256;            // [0,1024)
    int row = sg>>4, bk = sg&15;
    *(hf8*)&Sp[row*SPAD2 + bk*8] = *(const hf8*)(sp + row*DS + bk*8);
  }
  __syncthreads();
  f32x4 acc[4][2];
  #pragma unroll
  for (int i=0;i<4;i++){ acc[i][0]=(f32x4){0,0,0,0}; acc[i][1]=(f32x4){0,0,0,0}; }
  #pragma unroll
  for (int kk=0; kk<4; ++kk){
    hf8 fa[4], fb[2];
    #pragma unroll
    for (int i=0;i<4;i++) fa[i] = *(const hf8*)&Csc[(wr*64+i*16+lm)*SPAD2 + kk*32 + kg*8];
    #pragma unroll
    for (int j=0;j<2;j++) fb[j] = *(const hf8*)&Sp[(wc*32+j*16+lm)*SPAD2 + kk*32 + kg*8];
    #pragma unroll
    for (int i=0;i<4;i++)
      #pragma unroll
      for (int j=0;j<2;j++)
        acc[i][j] = __builtin_amdgcn_mfma_f32_16x16x32_f16(fa[i], fb[j], acc[i][j], 0,0,0);
  }
  float Dh = Dp[h];
  size_t yb = ((size_t)bh*NCH + c)*(HD*QC);
  #pragma unroll
  for (int it=0;it<4;it++)
    #pragma unroll
    for (int jt=0;jt<2;jt++){
      int p_ = wc*32 + jt*16 + lm;
      int i0 = wr*64 + it*16 + kg*4;
      hf4 yi = *(const hf4*)&g_yintra[yb + (size_t)p_*QC + i0];
      #pragma unroll
      for (int r=0;r<4;r++){
        int i_ = i0 + r;
        size_t t = rb + i_;
        float xv = (float)g_xbc[t*CONVD + h*HD + p_];
        float zv = (float)g_zx [t*NPAD  + h*HD + p_];
        float y = acc[it][jt][r] + (float)yi[r] + Dh*xv;
        g_xbc[t*CONVD + h*HD + p_] = (f16)(y * silu_f(zv));
      }
    }
}

// ---- RMSNorm of gated y -> f16 ----
__global__ __launch_bounds__(256) void k_rms(const float* __restrict__ nw){
  int r = blockIdx.x, tid = threadIdx.x;
  const f16* yr = g_xbc + (size_t)r*CONVD;
  float v[6]; float q = 0.f;
  #pragma unroll
  for (int i=0;i<6;i++){ v[i] = (float)yr[tid + i*256]; q += v[i]*v[i]; }
  __shared__ float red[4];
  #pragma unroll
  for (int o=32;o>0;o>>=1) q += __shfl_down(q,o);
  if ((tid&63)==0) red[tid>>6] = q;
  __syncthreads();
  float qt = red[0]+red[1]+red[2]+red[3];
  float sc = rsqrtf(qt*(1.f/DI) + 1e-5f);
  f16* dst = g_yn + (size_t)r*DI;
  #pragma unroll
  for (int i=0;i<6;i++) dst[tid + i*256] = (f16)(v[i]*sc*nw[tid + i*256]);
}

extern "C" void kernel_launch(void* const* d_in, const int* in_sizes, int n_in,
                              void* d_out, int out_size, void* d_ws, size_t ws_size,
                              hipStream_t stream){
  const float* x    = (const float*)d_in[0];
  const float* Win  = (const float*)d_in[1];
  const float* cw   = (const float*)d_in[2];
  const float* cbv  = (const float*)d_in[3];
  const float* dtb  = (const float*)d_in[4];
  const float* alog = (const float*)d_in[5];
  const float* Dv   = (const float*)d_in[6];
  const float* nw   = (const float*)d_in[7];
  const float* Wout = (const float*)d_in[8];
  const float* lnw  = (const float*)d_in[9];
  const float* lnb  = (const float*)d_in[10];
  float* out = (float*)d_out;

  k_castWin <<<(NPAD*DM)/256, 256, 0, stream>>>(Win);
  k_castWout<<<(DM*DI)/256,   256, 0, stream>>>(Wout);
  k_ln      <<<BL,            256, 0, stream>>>(x, lnw, lnb);
  k_gemm1   <<<(BL/256)*(NPAD/256), 512, 0, stream>>>();
  k_conv    <<<((BL/8)*CONVD)/256, 256, 0, stream>>>(cw, cbv);
  k_dadt    <<<(BQ*NH*LQ)/256, 256, 0, stream>>>(dtb, alog);
  k_gpre    <<<BQ*NCH,        256, 0, stream>>>();
  k_ssd_a   <<<BQ*NCH*NH,     512, 0, stream>>>();
  k_ssd_b   <<<BQ*NH*32,      256, 0, stream>>>();
  k_ssd_c   <<<BQ*NCH*NH,     256, 0, stream>>>(Dv);
  k_rms     <<<BL,            256, 0, stream>>>(nw);
  k_gemm2   <<<(BL/256)*(DM/256), 512, 0, stream>>>(out, x);
}